// Round 2
// baseline (621.327 us; speedup 1.0000x reference)
//
#include <hip/hip_runtime.h>
#include <hip/hip_bf16.h>
#include <math.h>

typedef __attribute__((ext_vector_type(8))) short short8;
typedef __attribute__((ext_vector_type(4))) float floatx4;

__device__ __forceinline__ unsigned short bfb(float x) {
    union { __hip_bfloat16 h; unsigned short u; } c;
    c.h = __float2bfloat16(x);
    return c.u;
}
__device__ __forceinline__ float bf2f(unsigned short u) {
    union { unsigned int i; float f; } c;
    c.i = ((unsigned int)u) << 16;
    return c.f;
}
// packed unsigned 16-bit max (gfx9 VOP3P, inherited on CDNA4)
__device__ __forceinline__ unsigned pkmaxu16(unsigned a, unsigned b) {
    unsigned d;
    asm("v_pk_max_u16 %0, %1, %2" : "=v"(d) : "v"(a), "v"(b));
    return d;
}

// ---------------- bucketed CSR build v3 ----------------

__global__ __launch_bounds__(256) void k_bhist(const int* __restrict__ dst, int* __restrict__ bcnt, int E) {
    __shared__ int h[512];
    int t = threadIdx.x;
    for (int i = t; i < 512; i += 256) h[i] = 0;
    __syncthreads();
    int step = gridDim.x * 256;
    for (int i = blockIdx.x * 256 + t; i < E; i += step) atomicAdd(&h[dst[i] >> 8], 1);
    __syncthreads();
    for (int i = t; i < 512; i += 256) if (h[i]) atomicAdd(&bcnt[i], h[i]);
}

__global__ __launch_bounds__(512) void k_scanBkt(const int* __restrict__ bcnt, int* __restrict__ boff,
                                                 int* __restrict__ bcur, int nb, int E) {
    __shared__ int s[512];
    int t = threadIdx.x;
    int v = (t < nb) ? bcnt[t] : 0;
    s[t] = v;
    __syncthreads();
    for (int off = 1; off < 512; off <<= 1) {
        int x = (t >= off) ? s[t - off] : 0;
        __syncthreads();
        s[t] += x;
        __syncthreads();
    }
    if (t < nb) { boff[t] = s[t] - v; bcur[t] = s[t] - v; }
    if (t == 0) boff[nb] = E;
}

#define PCHUNK 8192

__global__ __launch_bounds__(256) void k_partA(const int* __restrict__ src, const int* __restrict__ dst,
                                               int* __restrict__ bcur, unsigned* __restrict__ ebuf, int E) {
    __shared__ int h[512];
    __shared__ int base[512];
    int t = threadIdx.x;
    for (int i = t; i < 512; i += 256) h[i] = 0;
    __syncthreads();
    int start = blockIdx.x * PCHUNK;
    int end = start + PCHUNK < E ? start + PCHUNK : E;
    for (int i = start + t; i < end; i += 256) atomicAdd(&h[dst[i] >> 8], 1);
    __syncthreads();
    for (int i = t; i < 512; i += 256) {
        int c = h[i];
        base[i] = c ? atomicAdd(&bcur[i], c) : 0;
        h[i] = 0;
    }
    __syncthreads();
    for (int i = start + t; i < end; i += 256) {
        int d = dst[i];
        int b = d >> 8;
        int r = atomicAdd(&h[b], 1);
        ebuf[base[b] + r] = ((unsigned)src[i] << 8) | (unsigned)(d & 255);
    }
}

__global__ __launch_bounds__(256) void k_finish(const unsigned* __restrict__ ebuf, const int* __restrict__ boff,
                                                int* __restrict__ row_off, float* __restrict__ dinv,
                                                int* __restrict__ csr, int N, int E) {
    __shared__ int h[256];
    __shared__ int sc[256];
    __shared__ int cur[256];
    int b = blockIdx.x, t = threadIdx.x;
    h[t] = 0;
    __syncthreads();
    int beg = boff[b], end = boff[b + 1];
    for (int e = beg + t; e < end; e += 256) atomicAdd(&h[ebuf[e] & 255], 1);
    __syncthreads();
    int v = h[t];
    sc[t] = v;
    __syncthreads();
    for (int off = 1; off < 256; off <<= 1) {
        int x = (t >= off) ? sc[t - off] : 0;
        __syncthreads();
        sc[t] += x;
        __syncthreads();
    }
    int node = (b << 8) + t;
    int excl = beg + sc[t] - v;
    if (node < N) {
        row_off[node] = excl;
        dinv[node] = rsqrtf((float)(v > 1 ? v : 1));
    }
    cur[t] = excl;
    if (b == 0 && t == 0) row_off[N] = E;
    __syncthreads();
    for (int e = beg + t; e < end; e += 256) {
        unsigned ed = ebuf[e];
        int pos = atomicAdd(&cur[ed & 255], 1);
        csr[pos] = (int)(ed >> 8);
    }
}

// ---------------- feat -> bf16 pre-scaled ----------------

__global__ __launch_bounds__(256) void k_feat16(const float* __restrict__ feat, const float* __restrict__ dinv,
                                                unsigned short* __restrict__ featd, int total) {
    int i = blockIdx.x * 256 + threadIdx.x;
    if (i < total) featd[i] = bfb(feat[i] * dinv[i >> 4]);
}

// ---------------- 16-dim Chebyshev aggregation, wave-per-node (R14) ----------------
// 16 edge-groups x 4-col ushort4 loads: 4x fewer VMEM instrs than thread-per-col.

__global__ __launch_bounds__(256) void k_aggr16(const unsigned short* __restrict__ Xd, const float* __restrict__ Z,
                                                const float* __restrict__ dinv,
                                                const int* __restrict__ row_off, const int* __restrict__ csr,
                                                float* __restrict__ out, unsigned short* __restrict__ outd,
                                                float alpha, float beta, int N) {
    int node = blockIdx.x * 4 + (threadIdx.x >> 6);
    if (node >= N) return;
    int lane = threadIdx.x & 63;
    int g = lane >> 2;                  // 16 edge groups
    int co = (lane & 3) * 8;            // byte offset of this lane's 4 cols
    int beg = row_off[node], end = row_off[node + 1];
    int deg = end - beg;
    int myOff = ((lane < deg) ? csr[beg + lane] : 0) << 5;   // 32B rows
    int dmain = deg < 64 ? deg : 64;
    float a0 = 0.f, a1 = 0.f, a2 = 0.f, a3 = 0.f;
    int j = 0;
    for (; j + 15 < dmain; j += 16) {
        int off = __shfl(myOff, j + g);
        ushort4 x = *(const ushort4*)((const char*)Xd + off + co);
        a0 += bf2f(x.x); a1 += bf2f(x.y); a2 += bf2f(x.z); a3 += bf2f(x.w);
    }
    if (j < dmain) {
        int idx = j + g;
        int off = __shfl(myOff, idx < dmain ? idx : dmain - 1);
        ushort4 x = *(const ushort4*)((const char*)Xd + off + co);
        if (idx < dmain) {
            a0 += bf2f(x.x); a1 += bf2f(x.y); a2 += bf2f(x.z); a3 += bf2f(x.w);
        }
    }
    for (int e = beg + 64; e < end; e += 16) {   // deg>64: essentially never
        int idx = e + g;
        int s = csr[idx < end ? idx : end - 1];
        ushort4 x = *(const ushort4*)((const char*)Xd + (s << 5) + co);
        if (idx < end) {
            a0 += bf2f(x.x); a1 += bf2f(x.y); a2 += bf2f(x.z); a3 += bf2f(x.w);
        }
    }
    a0 += __shfl_xor(a0, 4); a0 += __shfl_xor(a0, 8); a0 += __shfl_xor(a0, 16); a0 += __shfl_xor(a0, 32);
    a1 += __shfl_xor(a1, 4); a1 += __shfl_xor(a1, 8); a1 += __shfl_xor(a1, 16); a1 += __shfl_xor(a1, 32);
    a2 += __shfl_xor(a2, 4); a2 += __shfl_xor(a2, 8); a2 += __shfl_xor(a2, 16); a2 += __shfl_xor(a2, 32);
    a3 += __shfl_xor(a3, 4); a3 += __shfl_xor(a3, 8); a3 += __shfl_xor(a3, 16); a3 += __shfl_xor(a3, 32);
    if (g == 0) {
        int c4 = (lane & 3) * 4;
        float dn = dinv[node];
        float v0 = alpha * dn * a0;
        float v1 = alpha * dn * a1;
        float v2 = alpha * dn * a2;
        float v3 = alpha * dn * a3;
        if (Z) {
            float4 zv = *(const float4*)&Z[(size_t)node * 16 + c4];
            v0 += beta * zv.x; v1 += beta * zv.y; v2 += beta * zv.z; v3 += beta * zv.w;
        }
        float4 r = { v0, v1, v2, v3 };
        *(float4*)&out[(size_t)node * 16 + c4] = r;
        if (outd) {
            ushort4 u = { bfb(v0 * dn), bfb(v1 * dn), bfb(v2 * dn), bfb(v3 * dn) };
            *(ushort4*)&outd[(size_t)node * 16 + c4] = u;
        }
    }
}

// ---------------- 64-dim Chebyshev aggregation (R13 + byte-offset preshift) ----------------

__global__ __launch_bounds__(256) void k_aggr64(const unsigned short* __restrict__ Xd, const float* __restrict__ Z,
                                                const float* __restrict__ dinv,
                                                const int* __restrict__ row_off, const int* __restrict__ csr,
                                                unsigned short* __restrict__ outb, unsigned short* __restrict__ outd,
                                                float alpha, float beta, int N) {
    int node = blockIdx.x * 4 + (threadIdx.x >> 6);
    if (node >= N) return;
    int lane = threadIdx.x & 63;
    int g = lane >> 4;
    int co = (lane & 15) * 8;           // byte offset of this lane's 4 cols
    int beg = row_off[node], end = row_off[node + 1];
    int deg = end - beg;
    int myOff = ((lane < deg) ? csr[beg + lane] : 0) << 7;   // 128B rows
    int dmain = deg < 64 ? deg : 64;
    float a0 = 0.f, a1 = 0.f, a2 = 0.f, a3 = 0.f;
    float b0 = 0.f, b1 = 0.f, b2 = 0.f, b3 = 0.f;
    int j = 0;
    for (; j + 15 < dmain; j += 16) {
        int oA = __shfl(myOff, j + g);
        int oB = __shfl(myOff, j + 4 + g);
        int oC = __shfl(myOff, j + 8 + g);
        int oD = __shfl(myOff, j + 12 + g);
        ushort4 xA = *(const ushort4*)((const char*)Xd + oA + co);
        ushort4 xB = *(const ushort4*)((const char*)Xd + oB + co);
        ushort4 xC = *(const ushort4*)((const char*)Xd + oC + co);
        ushort4 xD = *(const ushort4*)((const char*)Xd + oD + co);
        a0 += bf2f(xA.x); a1 += bf2f(xA.y); a2 += bf2f(xA.z); a3 += bf2f(xA.w);
        b0 += bf2f(xB.x); b1 += bf2f(xB.y); b2 += bf2f(xB.z); b3 += bf2f(xB.w);
        a0 += bf2f(xC.x); a1 += bf2f(xC.y); a2 += bf2f(xC.z); a3 += bf2f(xC.w);
        b0 += bf2f(xD.x); b1 += bf2f(xD.y); b2 += bf2f(xD.z); b3 += bf2f(xD.w);
    }
    for (; j + 7 < dmain; j += 8) {
        int oA = __shfl(myOff, j + g);
        int oB = __shfl(myOff, j + 4 + g);
        ushort4 xA = *(const ushort4*)((const char*)Xd + oA + co);
        ushort4 xB = *(const ushort4*)((const char*)Xd + oB + co);
        a0 += bf2f(xA.x); a1 += bf2f(xA.y); a2 += bf2f(xA.z); a3 += bf2f(xA.w);
        b0 += bf2f(xB.x); b1 += bf2f(xB.y); b2 += bf2f(xB.z); b3 += bf2f(xB.w);
    }
    for (; j < dmain; j += 4) {
        int idx = j + g;
        int off = __shfl(myOff, idx < dmain ? idx : dmain - 1);
        ushort4 x = *(const ushort4*)((const char*)Xd + off + co);
        if (idx < dmain) {
            a0 += bf2f(x.x); a1 += bf2f(x.y); a2 += bf2f(x.z); a3 += bf2f(x.w);
        }
    }
    for (int e = beg + 64; e < end; e += 4) {    // deg>64: essentially never
        int idx = e + g;
        int s = csr[idx < end ? idx : end - 1];
        ushort4 x = *(const ushort4*)((const char*)Xd + (s << 7) + co);
        if (idx < end) {
            a0 += bf2f(x.x); a1 += bf2f(x.y); a2 += bf2f(x.z); a3 += bf2f(x.w);
        }
    }
    a0 += b0; a1 += b1; a2 += b2; a3 += b3;
    a0 += __shfl_xor(a0, 16); a0 += __shfl_xor(a0, 32);
    a1 += __shfl_xor(a1, 16); a1 += __shfl_xor(a1, 32);
    a2 += __shfl_xor(a2, 16); a2 += __shfl_xor(a2, 32);
    a3 += __shfl_xor(a3, 16); a3 += __shfl_xor(a3, 32);
    if (g == 0) {
        int c4 = (lane & 15) * 4;
        float dn = dinv[node];
        float v0 = alpha * dn * a0;
        float v1 = alpha * dn * a1;
        float v2 = alpha * dn * a2;
        float v3 = alpha * dn * a3;
        if (Z) {
            float4 zv = *(const float4*)&Z[(size_t)node * 64 + c4];
            v0 += beta * zv.x; v1 += beta * zv.y; v2 += beta * zv.z; v3 += beta * zv.w;
        }
        ushort4 ub = { bfb(v0), bfb(v1), bfb(v2), bfb(v3) };
        *(ushort4*)&outb[(size_t)node * 64 + c4] = ub;
        if (outd) {
            ushort4 u = { bfb(v0 * dn), bfb(v1 * dn), bfb(v2 * dn), bfb(v3 * dn) };
            *(ushort4*)&outd[(size_t)node * 64 + c4] = u;
        }
    }
}

// ---------------- Cheb matmul via MFMA 16x16x32 bf16 ----------------

template <int KDIM, bool BIN16, bool BOUT16>
__global__ __launch_bounds__(256) void k_cheb_m(const float* __restrict__ X0, const void* __restrict__ X1v,
                                                const void* __restrict__ X2v, const float* __restrict__ W,
                                                const float* __restrict__ b, void* __restrict__ outv, int N) {
    constexpr int KT = (KDIM == 16) ? 64 : 3 * KDIM;
    constexpr int SX = KT + 8;
    __shared__ unsigned short Xs[64 * SX];
    __shared__ unsigned short Ws[64 * SX];
    int t = threadIdx.x;

    {
        int sn = t & 63;
        int gn = blockIdx.x * 64 + sn; if (gn >= N) gn = N - 1;
        int k0 = (t >> 6) * (KDIM / 4);
#pragma unroll
        for (int i = 0; i < KDIM / 16; ++i) {
            float4 v = *(const float4*)&X0[(size_t)gn * KDIM + k0 + 4 * i];
            ushort4 u = { bfb(v.x), bfb(v.y), bfb(v.z), bfb(v.w) };
            *(ushort4*)&Xs[sn * SX + k0 + 4 * i] = u;
        }
        if constexpr (BIN16) {
            const unsigned short* X1 = (const unsigned short*)X1v;
            const unsigned short* X2 = (const unsigned short*)X2v;
#pragma unroll
            for (int i = 0; i < KDIM / 16; ++i) {
                *(ushort4*)&Xs[sn * SX + KDIM + k0 + 4 * i] =
                    *(const ushort4*)&X1[(size_t)gn * KDIM + k0 + 4 * i];
                *(ushort4*)&Xs[sn * SX + 2 * KDIM + k0 + 4 * i] =
                    *(const ushort4*)&X2[(size_t)gn * KDIM + k0 + 4 * i];
            }
        } else {
            const float* Xp[2] = { (const float*)X1v, (const float*)X2v };
#pragma unroll
            for (int a = 0; a < 2; ++a) {
#pragma unroll
                for (int i = 0; i < KDIM / 16; ++i) {
                    float4 v = *(const float4*)&Xp[a][(size_t)gn * KDIM + k0 + 4 * i];
                    ushort4 u = { bfb(v.x), bfb(v.y), bfb(v.z), bfb(v.w) };
                    *(ushort4*)&Xs[sn * SX + (a + 1) * KDIM + k0 + 4 * i] = u;
                }
            }
        }
        if (KDIM == 16) {
            int kp = 48 + (t >> 6) * 4;
            ushort4 z = { 0, 0, 0, 0 };
            *(ushort4*)&Xs[sn * SX + kp] = z;
        }
    }
    for (int idx = t; idx < 3 * KDIM * 64; idx += 256) {
        int a = idx / (KDIM * 64);
        int r = idx % (KDIM * 64);
        int k = r >> 6, n = r & 63;
        Ws[n * SX + a * KDIM + k] = bfb(W[idx]);
    }
    if (KDIM == 16) {
        for (int idx = t; idx < 1024; idx += 256) {
            int n = idx & 63, k = 48 + (idx >> 6);
            Ws[n * SX + k] = 0;
        }
    }
    __syncthreads();

    int wave = t >> 6, lane = t & 63;
    int fi = lane & 15, quad = lane >> 4;
    int arow = wave * 16 + fi;

    floatx4 acc0 = {0.f,0.f,0.f,0.f}, acc1 = {0.f,0.f,0.f,0.f}, acc2 = {0.f,0.f,0.f,0.f}, acc3 = {0.f,0.f,0.f,0.f};
#pragma unroll
    for (int ks = 0; ks < KT / 32; ++ks) {
        short8 af = *(const short8*)&Xs[arow * SX + ks * 32 + quad * 8];
        short8 b0 = *(const short8*)&Ws[(0 * 16 + fi) * SX + ks * 32 + quad * 8];
        short8 b1 = *(const short8*)&Ws[(1 * 16 + fi) * SX + ks * 32 + quad * 8];
        short8 b2 = *(const short8*)&Ws[(2 * 16 + fi) * SX + ks * 32 + quad * 8];
        short8 b3 = *(const short8*)&Ws[(3 * 16 + fi) * SX + ks * 32 + quad * 8];
        acc0 = __builtin_amdgcn_mfma_f32_16x16x32_bf16(af, b0, acc0, 0, 0, 0);
        acc1 = __builtin_amdgcn_mfma_f32_16x16x32_bf16(af, b1, acc1, 0, 0, 0);
        acc2 = __builtin_amdgcn_mfma_f32_16x16x32_bf16(af, b2, acc2, 0, 0, 0);
        acc3 = __builtin_amdgcn_mfma_f32_16x16x32_bf16(af, b3, acc3, 0, 0, 0);
    }

    int nbase = blockIdx.x * 64 + wave * 16 + quad * 4;
    floatx4 accs[4] = { acc0, acc1, acc2, acc3 };
#pragma unroll
    for (int nt = 0; nt < 4; ++nt) {
        int col = nt * 16 + fi;
        float bias = b[col];
#pragma unroll
        for (int reg = 0; reg < 4; ++reg) {
            int node = nbase + reg;
            if (node < N) {
                float r = fmaxf(accs[nt][reg] + bias, 0.f);
                if constexpr (BOUT16) {
                    ((unsigned short*)outv)[(size_t)node * 64 + col] = bfb(r);
                } else {
                    ((float*)outv)[(size_t)node * 64 + col] = r;
                }
            }
        }
    }
}

// ---------------- EdgeConv stage 1 via MFMA: [m|p] = X @ [Wt | Wt+Wp] ----------------
// md now stores ORDER-KEYS of (-theta): key = (u&0x8000) ? u : u^0x7fff, u = bf16(-v)
// ... equivalently computed directly from u=bf16(v) as (u&0x8000)?u: u^0x7fff after
// sign flip; here we flip sign first then map. Consumer k_e2_b does packed u16 max.

__global__ __launch_bounds__(256) void k_e1_m(const unsigned short* X, const float* __restrict__ Wt,
                                              const float* __restrict__ Wp, const float* __restrict__ bt,
                                              const float* __restrict__ bp,
                                              unsigned short* md, float* __restrict__ pbuf, int N) {
    constexpr int SX = 72;
    __shared__ unsigned short Xs[64 * SX];
    __shared__ unsigned short Ws[128 * SX];
    int t = threadIdx.x;

    {
        int sn = t & 63;
        int gn = blockIdx.x * 64 + sn; if (gn >= N) gn = N - 1;
        int k0 = (t >> 6) * 16;
#pragma unroll
        for (int i = 0; i < 2; ++i) {
            *(short8*)&Xs[sn * SX + k0 + 8 * i] = *(const short8*)&X[(size_t)gn * 64 + k0 + 8 * i];
        }
    }
    for (int idx = t; idx < 4096; idx += 256) {
        int k = idx >> 6, n = idx & 63;
        float wt = Wt[idx];
        Ws[n * SX + k] = bfb(wt);
        Ws[(64 + n) * SX + k] = bfb(wt + Wp[idx]);
    }
    __syncthreads();

    int wave = t >> 6, lane = t & 63;
    int fi = lane & 15, quad = lane >> 4;
    int arow = wave * 16 + fi;

    floatx4 acc[8];
#pragma unroll
    for (int i = 0; i < 8; ++i) acc[i] = (floatx4){0.f,0.f,0.f,0.f};
#pragma unroll
    for (int ks = 0; ks < 2; ++ks) {
        short8 af = *(const short8*)&Xs[arow * SX + ks * 32 + quad * 8];
#pragma unroll
        for (int nt = 0; nt < 8; ++nt) {
            short8 bf = *(const short8*)&Ws[(nt * 16 + fi) * SX + ks * 32 + quad * 8];
            acc[nt] = __builtin_amdgcn_mfma_f32_16x16x32_bf16(af, bf, acc[nt], 0, 0, 0);
        }
    }

    int nbase = blockIdx.x * 64 + wave * 16 + quad * 4;
#pragma unroll
    for (int nt = 0; nt < 8; ++nt) {
        int col = nt * 16 + fi;
        if (col < 64) {
#pragma unroll
            for (int reg = 0; reg < 4; ++reg) {
                int node = nbase + reg;
                if (node < N) {
                    // key of (-v): u = bf16(v); negate = u^0x8000; monotone map.
                    unsigned u = (unsigned)bfb(acc[nt][reg]) ^ 0x8000u;
                    unsigned key = (u & 0x8000u) ? (~u & 0xffffu) : (u | 0x8000u);
                    md[(size_t)node * 64 + col] = (unsigned short)key;
                }
            }
        } else {
            int cc = col - 64;
            float bias = bt[cc] + bp[cc];
#pragma unroll
            for (int reg = 0; reg < 4; ++reg) {
                int node = nbase + reg;
                if (node < N) pbuf[(size_t)node * 64 + cc] = acc[nt][reg] + bias;
            }
        }
    }
}

// ---------------- EdgeConv stage 2: packed u16 key-max gather (R14) ----------------
// md holds monotone keys of (-theta); inner loop is pure v_pk_max_u16 on uint32
// pairs (2 keys each). Decode back to bf16 once per node after the reduce.

__global__ __launch_bounds__(256) void k_e2_b(const unsigned short* __restrict__ md, const float* __restrict__ pbuf,
                                              const int* __restrict__ row_off, const int* __restrict__ csr,
                                              const float* __restrict__ dinv, float* __restrict__ out,
                                              unsigned short* __restrict__ outd, int N) {
    int node = blockIdx.x * 4 + (threadIdx.x >> 6);
    if (node >= N) return;
    int lane = threadIdx.x & 63;
    int g = lane >> 4;
    int co = (lane & 15) * 8;           // byte offset of this lane's 4 cols
    int beg = row_off[node], end = row_off[node + 1];
    int deg = end - beg;
    int myOff = ((lane < deg) ? csr[beg + lane] : 0) << 7;   // 128B rows
    int dmain = deg < 64 ? deg : 64;
    unsigned kA0 = 0, kA1 = 0, kB0 = 0, kB1 = 0;   // 0 < every real key
    int j = 0;
    for (; j + 15 < dmain; j += 16) {
        int oA = __shfl(myOff, j + g);
        int oB = __shfl(myOff, j + 4 + g);
        int oC = __shfl(myOff, j + 8 + g);
        int oD = __shfl(myOff, j + 12 + g);
        uint2 xA = *(const uint2*)((const char*)md + oA + co);
        uint2 xB = *(const uint2*)((const char*)md + oB + co);
        uint2 xC = *(const uint2*)((const char*)md + oC + co);
        uint2 xD = *(const uint2*)((const char*)md + oD + co);
        kA0 = pkmaxu16(kA0, xA.x); kA1 = pkmaxu16(kA1, xA.y);
        kB0 = pkmaxu16(kB0, xB.x); kB1 = pkmaxu16(kB1, xB.y);
        kA0 = pkmaxu16(kA0, xC.x); kA1 = pkmaxu16(kA1, xC.y);
        kB0 = pkmaxu16(kB0, xD.x); kB1 = pkmaxu16(kB1, xD.y);
    }
    for (; j + 7 < dmain; j += 8) {
        int oA = __shfl(myOff, j + g);
        int oB = __shfl(myOff, j + 4 + g);
        uint2 xA = *(const uint2*)((const char*)md + oA + co);
        uint2 xB = *(const uint2*)((const char*)md + oB + co);
        kA0 = pkmaxu16(kA0, xA.x); kA1 = pkmaxu16(kA1, xA.y);
        kB0 = pkmaxu16(kB0, xB.x); kB1 = pkmaxu16(kB1, xB.y);
    }
    for (; j < dmain; j += 4) {
        int idx = j + g;
        int off = __shfl(myOff, idx < dmain ? idx : dmain - 1);
        uint2 x = *(const uint2*)((const char*)md + off + co);
        kA0 = pkmaxu16(kA0, idx < dmain ? x.x : 0u);
        kA1 = pkmaxu16(kA1, idx < dmain ? x.y : 0u);
    }
    for (int e = beg + 64; e < end; e += 4) {    // deg>64: essentially never
        int idx = e + g;
        int s = csr[idx < end ? idx : end - 1];
        uint2 x = *(const uint2*)((const char*)md + (s << 7) + co);
        kA0 = pkmaxu16(kA0, idx < end ? x.x : 0u);
        kA1 = pkmaxu16(kA1, idx < end ? x.y : 0u);
    }
    kA0 = pkmaxu16(kA0, kB0); kA1 = pkmaxu16(kA1, kB1);
    kA0 = pkmaxu16(kA0, __shfl_xor((int)kA0, 16)); kA0 = pkmaxu16(kA0, __shfl_xor((int)kA0, 32));
    kA1 = pkmaxu16(kA1, __shfl_xor((int)kA1, 16)); kA1 = pkmaxu16(kA1, __shfl_xor((int)kA1, 32));
    if (g == 0) {
        int c4 = (lane & 15) * 4;
        unsigned short ks[4] = { (unsigned short)(kA0 & 0xffff), (unsigned short)(kA0 >> 16),
                                 (unsigned short)(kA1 & 0xffff), (unsigned short)(kA1 >> 16) };
        float a[4];
#pragma unroll
        for (int i = 0; i < 4; ++i) {
            unsigned k = ks[i];
            unsigned short tt = (k & 0x8000u) ? (unsigned short)(k & 0x7fffu) : (unsigned short)(~k & 0xffffu);
            a[i] = bf2f(tt);
        }
        float r0 = 0.f, r1 = 0.f, r2 = 0.f, r3 = 0.f;
        if (end > beg) {
            float4 pv = *(const float4*)&pbuf[(size_t)node * 64 + c4];
            r0 = fmaxf(pv.x + a[0], 0.f);
            r1 = fmaxf(pv.y + a[1], 0.f);
            r2 = fmaxf(pv.z + a[2], 0.f);
            r3 = fmaxf(pv.w + a[3], 0.f);
        }
        float4 r = { r0, r1, r2, r3 };
        *(float4*)&out[(size_t)node * 64 + c4] = r;
        float dn = dinv[node];
        ushort4 u = { bfb(r0 * dn), bfb(r1 * dn), bfb(r2 * dn), bfb(r3 * dn) };
        *(ushort4*)&outd[(size_t)node * 64 + c4] = u;
    }
}

// ---------------- graph mean pooling (segmented: gid is sorted) ----------------

__global__ __launch_bounds__(256) void k_pool(const float* __restrict__ h, const int* __restrict__ gid,
                                              float* __restrict__ out, float* __restrict__ gcnt, int N) {
    const int CHUNK = 128;
    int wave = blockIdx.x * 4 + (threadIdx.x >> 6);
    int lane = threadIdx.x & 63;
    int beg = wave * CHUNK;
    if (beg >= N) return;
    int end = beg + CHUNK < N ? beg + CHUNK : N;
    int gcur = gid[beg];
    float acc = 0.f;
    int cnt = 0;
    for (int n = beg; n < end; ++n) {
        int g = gid[n];
        float v = h[n * 64 + lane];
        if (g != gcur) {
            atomicAdd(&out[gcur * 64 + lane], acc);
            if (lane == 0) atomicAdd(&gcnt[gcur], (float)cnt);
            gcur = g; acc = 0.f; cnt = 0;
        }
        acc += v;
        ++cnt;
    }
    atomicAdd(&out[gcur * 64 + lane], acc);
    if (lane == 0) atomicAdd(&gcnt[gcur], (float)cnt);
}

__global__ __launch_bounds__(256) void k_div(float* __restrict__ out, const float* __restrict__ gcnt, int total) {
    int i = blockIdx.x * blockDim.x + threadIdx.x;
    if (i < total) out[i] /= fmaxf(gcnt[i >> 6], 1.f);
}

// ---------------- launcher ----------------

extern "C" void kernel_launch(void* const* d_in, const int* in_sizes, int n_in,
                              void* d_out, int out_size, void* d_ws, size_t ws_size,
                              hipStream_t stream) {
    const float* feat = (const float*)d_in[0];
    const int* src = (const int*)d_in[1];
    const int* dst = (const int*)d_in[2];
    const int* gid = (const int*)d_in[3];
    const float* W1 = (const float*)d_in[4];  const float* b1 = (const float*)d_in[5];
    const float* W2 = (const float*)d_in[6];  const float* b2 = (const float*)d_in[7];
    const float* W3 = (const float*)d_in[8];  const float* b3 = (const float*)d_in[9];
    const float* Wt1 = (const float*)d_in[10]; const float* bt1 = (const float*)d_in[11];
    const float* Wp1 = (const float*)d_in[12]; const float* bp1 = (const float*)d_in[13];
    const float* Wt2 = (const float*)d_in[14]; const float* bt2 = (const float*)d_in[15];
    const float* Wp2 = (const float*)d_in[16]; const float* bp2 = (const float*)d_in[17];
    float* out = (float*)d_out;

    const int N = in_sizes[0] / 16;
    const int E = in_sizes[1];
    const int G = out_size / 64;
    const int nb = (N + 255) >> 8;      // buckets (<= 512)

    char* p = (char*)d_ws;
    auto alloc = [&](size_t nbytes) {
        void* r = (void*)p;
        p += (nbytes + 255) & ~(size_t)255;
        return r;
    };
    int* row_off  = (int*)alloc((size_t)(N + 1) * 4);
    int* csr      = (int*)alloc((size_t)E * 4);
    int* bcnt     = (int*)alloc(512 * 4);
    int* boff     = (int*)alloc(513 * 4);
    int* bcur     = (int*)alloc(512 * 4);
    float* dinv   = (float*)alloc((size_t)N * 4);
    float* bufA   = (float*)alloc((size_t)N * 64 * 4);
    float* bufB   = (float*)alloc((size_t)N * 64 * 4);
    float* bufC   = (float*)alloc((size_t)N * 64 * 4);
    float* bufD   = (float*)alloc((size_t)N * 64 * 4);
    unsigned short* md = (unsigned short*)alloc((size_t)N * 64 * 2);
    float* gcnt   = (float*)alloc((size_t)G * 4);

    unsigned* ebuf = (unsigned*)bufA;   // alias: bufA dead until after CSR build
    unsigned short* hd = (unsigned short*)bufC;
    unsigned short* xd = (unsigned short*)bufC + (size_t)N * 64;
    unsigned short* hb = md;            // cheb bf16 output; block-local r/w in k_e1_m is safe

    hipMemsetAsync(bcnt, 0, 512 * 4, stream);
    hipMemsetAsync(gcnt, 0, (size_t)G * 4, stream);
    hipMemsetAsync(d_out, 0, (size_t)out_size * 4, stream);

    const int nb16 = (N * 16 + 255) / 256;
    const int nbw = (N + 3) / 4;
    const int npool = ((N + 127) / 128 + 3) / 4;
    const int nbt = (N + 63) / 64;
    const int npart = (E + PCHUNK - 1) / PCHUNK;

    // ---- bucketed CSR build v3 (4 launches)
    k_bhist<<<256, 256, 0, stream>>>(dst, bcnt, E);
    k_scanBkt<<<1, 512, 0, stream>>>(bcnt, boff, bcur, nb, E);
    k_partA<<<npart, 256, 0, stream>>>(src, dst, bcur, ebuf, E);
    k_finish<<<nb, 256, 0, stream>>>(ebuf, boff, row_off, dinv, csr, N, E);

    // ---- Cheb layer 1 (IN=16)
    k_feat16<<<nb16, 256, 0, stream>>>(feat, dinv, hd, N * 16);
    k_aggr16<<<nbw, 256, 0, stream>>>(hd, nullptr, dinv, row_off, csr, bufA, xd, -1.f, 0.f, N);
    k_aggr16<<<nbw, 256, 0, stream>>>(xd, feat, dinv, row_off, csr, bufB, nullptr, -2.f, -1.f, N);
    k_cheb_m<16, false, true><<<nbt, 256, 0, stream>>>(feat, bufA, bufB, W1, b1, hb, N);

    // ---- EdgeConv 1
    k_e1_m<<<nbt, 256, 0, stream>>>(hb, Wt1, Wp1, bt1, bp1, md, bufB, N);
    k_e2_b<<<nbw, 256, 0, stream>>>(md, bufB, row_off, csr, dinv, bufD, hd, N);

    // ---- Cheb layer 2
    k_aggr64<<<nbw, 256, 0, stream>>>(hd, nullptr, dinv, row_off, csr, (unsigned short*)bufA, xd, -1.f, 0.f, N);
    k_aggr64<<<nbw, 256, 0, stream>>>(xd, bufD, dinv, row_off, csr, (unsigned short*)bufB, nullptr, -2.f, -1.f, N);
    k_cheb_m<64, true, true><<<nbt, 256, 0, stream>>>(bufD, bufA, bufB, W2, b2, hb, N);

    // ---- EdgeConv 2
    k_e1_m<<<nbt, 256, 0, stream>>>(hb, Wt2, Wp2, bt2, bp2, md, bufB, N);
    k_e2_b<<<nbw, 256, 0, stream>>>(md, bufB, row_off, csr, dinv, bufD, hd, N);

    // ---- Cheb layer 3 (fp32 out -> pooling, no extra rounding of final result)
    k_aggr64<<<nbw, 256, 0, stream>>>(hd, nullptr, dinv, row_off, csr, (unsigned short*)bufA, xd, -1.f, 0.f, N);
    k_aggr64<<<nbw, 256, 0, stream>>>(xd, bufD, dinv, row_off, csr, (unsigned short*)bufB, nullptr, -2.f, -1.f, N);
    k_cheb_m<64, true, false><<<nbt, 256, 0, stream>>>(bufD, bufA, bufB, W3, b3, bufC, N);

    // ---- per-graph mean pooling
    k_pool<<<npool, 256, 0, stream>>>(bufC, gid, out, gcnt, N);
    k_div<<<(out_size + 255) / 256, 256, 0, stream>>>(out, gcnt, out_size);
}

// Round 3
// 595.169 us; speedup vs baseline: 1.0439x; 1.0439x over previous
//
#include <hip/hip_runtime.h>
#include <hip/hip_bf16.h>
#include <math.h>

typedef __attribute__((ext_vector_type(8))) short short8;
typedef __attribute__((ext_vector_type(4))) float floatx4;

__device__ __forceinline__ unsigned short bfb(float x) {
    union { __hip_bfloat16 h; unsigned short u; } c;
    c.h = __float2bfloat16(x);
    return c.u;
}
__device__ __forceinline__ float bf2f(unsigned short u) {
    union { unsigned int i; float f; } c;
    c.i = ((unsigned int)u) << 16;
    return c.f;
}
// accumulate the two bf16 halves of a dword into two f32 accumulators
__device__ __forceinline__ void acc2(float& lo, float& hi, unsigned d) {
    union { unsigned u; float f; } a, b;
    a.u = d << 16;
    b.u = d & 0xffff0000u;
    lo += a.f; hi += b.f;
}
// packed unsigned 16-bit max (gfx9 VOP3P, inherited on CDNA4)
__device__ __forceinline__ unsigned pkmaxu16(unsigned a, unsigned b) {
    unsigned d;
    asm("v_pk_max_u16 %0, %1, %2" : "=v"(d) : "v"(a), "v"(b));
    return d;
}

// ---------------- bucketed CSR build v3 ----------------

__global__ __launch_bounds__(256) void k_bhist(const int* __restrict__ dst, int* __restrict__ bcnt, int E) {
    __shared__ int h[512];
    int t = threadIdx.x;
    for (int i = t; i < 512; i += 256) h[i] = 0;
    __syncthreads();
    int step = gridDim.x * 256;
    for (int i = blockIdx.x * 256 + t; i < E; i += step) atomicAdd(&h[dst[i] >> 8], 1);
    __syncthreads();
    for (int i = t; i < 512; i += 256) if (h[i]) atomicAdd(&bcnt[i], h[i]);
}

__global__ __launch_bounds__(512) void k_scanBkt(const int* __restrict__ bcnt, int* __restrict__ boff,
                                                 int* __restrict__ bcur, int nb, int E) {
    __shared__ int s[512];
    int t = threadIdx.x;
    int v = (t < nb) ? bcnt[t] : 0;
    s[t] = v;
    __syncthreads();
    for (int off = 1; off < 512; off <<= 1) {
        int x = (t >= off) ? s[t - off] : 0;
        __syncthreads();
        s[t] += x;
        __syncthreads();
    }
    if (t < nb) { boff[t] = s[t] - v; bcur[t] = s[t] - v; }
    if (t == 0) boff[nb] = E;
}

#define PCHUNK 8192

__global__ __launch_bounds__(256) void k_partA(const int* __restrict__ src, const int* __restrict__ dst,
                                               int* __restrict__ bcur, unsigned* __restrict__ ebuf, int E) {
    __shared__ int h[512];
    __shared__ int base[512];
    int t = threadIdx.x;
    for (int i = t; i < 512; i += 256) h[i] = 0;
    __syncthreads();
    int start = blockIdx.x * PCHUNK;
    int end = start + PCHUNK < E ? start + PCHUNK : E;
    for (int i = start + t; i < end; i += 256) atomicAdd(&h[dst[i] >> 8], 1);
    __syncthreads();
    for (int i = t; i < 512; i += 256) {
        int c = h[i];
        base[i] = c ? atomicAdd(&bcur[i], c) : 0;
        h[i] = 0;
    }
    __syncthreads();
    for (int i = start + t; i < end; i += 256) {
        int d = dst[i];
        int b = d >> 8;
        int r = atomicAdd(&h[b], 1);
        ebuf[base[b] + r] = ((unsigned)src[i] << 8) | (unsigned)(d & 255);
    }
}

__global__ __launch_bounds__(256) void k_finish(const unsigned* __restrict__ ebuf, const int* __restrict__ boff,
                                                int* __restrict__ row_off, float* __restrict__ dinv,
                                                int* __restrict__ csr, int N, int E) {
    __shared__ int h[256];
    __shared__ int sc[256];
    __shared__ int cur[256];
    int b = blockIdx.x, t = threadIdx.x;
    h[t] = 0;
    __syncthreads();
    int beg = boff[b], end = boff[b + 1];
    for (int e = beg + t; e < end; e += 256) atomicAdd(&h[ebuf[e] & 255], 1);
    __syncthreads();
    int v = h[t];
    sc[t] = v;
    __syncthreads();
    for (int off = 1; off < 256; off <<= 1) {
        int x = (t >= off) ? sc[t - off] : 0;
        __syncthreads();
        sc[t] += x;
        __syncthreads();
    }
    int node = (b << 8) + t;
    int excl = beg + sc[t] - v;
    if (node < N) {
        row_off[node] = excl;
        dinv[node] = rsqrtf((float)(v > 1 ? v : 1));
    }
    cur[t] = excl;
    if (b == 0 && t == 0) row_off[N] = E;
    __syncthreads();
    for (int e = beg + t; e < end; e += 256) {
        unsigned ed = ebuf[e];
        int pos = atomicAdd(&cur[ed & 255], 1);
        csr[pos] = (int)(ed >> 8);
    }
}

// ---------------- feat -> bf16 pre-scaled ----------------

__global__ __launch_bounds__(256) void k_feat16(const float* __restrict__ feat, const float* __restrict__ dinv,
                                                unsigned short* __restrict__ featd, int total) {
    int i = blockIdx.x * 256 + threadIdx.x;
    if (i < total) featd[i] = bfb(feat[i] * dinv[i >> 4]);
}

// ---------------- 16-dim Chebyshev aggregation, padded branch-free (R15) ----------------
// 1 wave per node. 2 independent ushort4 gathers cover 32 edges (zero-page pad).

__global__ __launch_bounds__(256) void k_aggr16(const unsigned short* __restrict__ Xd, const float* __restrict__ Z,
                                                const float* __restrict__ dinv,
                                                const int* __restrict__ row_off, const int* __restrict__ csr,
                                                float* __restrict__ out, unsigned short* __restrict__ outd,
                                                float alpha, float beta, int zoff, int N) {
    int node = blockIdx.x * 4 + (threadIdx.x >> 6);
    if (node >= N) return;
    int lane = threadIdx.x & 63;
    int g = lane >> 2;                  // 16 edge groups
    int co = (lane & 3) * 8;            // byte offset of this lane's 4 cols
    int beg = row_off[node], end = row_off[node + 1];
    int deg = end - beg;
    int myOff = (lane < deg) ? (csr[beg + lane] << 5) : zoff;   // 32B rows; pad -> zero page
    const char* base = (const char*)Xd + co;
    float a0 = 0.f, a1 = 0.f, a2 = 0.f, a3 = 0.f;
    {
        int o0 = __shfl(myOff, g);
        int o1 = __shfl(myOff, 16 + g);
        ushort4 x0 = *(const ushort4*)(base + o0);
        ushort4 x1 = *(const ushort4*)(base + o1);
        a0 += bf2f(x0.x); a1 += bf2f(x0.y); a2 += bf2f(x0.z); a3 += bf2f(x0.w);
        a0 += bf2f(x1.x); a1 += bf2f(x1.y); a2 += bf2f(x1.z); a3 += bf2f(x1.w);
    }
    if (deg > 32) {
        int dmain = deg < 64 ? deg : 64;
        for (int j = 32; j < dmain; j += 16) {           // shfl overshoot -> zero page
            int o = __shfl(myOff, j + g);
            ushort4 x = *(const ushort4*)(base + o);
            a0 += bf2f(x.x); a1 += bf2f(x.y); a2 += bf2f(x.z); a3 += bf2f(x.w);
        }
        for (int e = beg + 64; e < end; e += 16) {       // deg>64: essentially never
            int idx = e + g;
            int s = csr[idx < end ? idx : end - 1];
            ushort4 x = *(const ushort4*)(base + (s << 5));
            if (idx < end) {
                a0 += bf2f(x.x); a1 += bf2f(x.y); a2 += bf2f(x.z); a3 += bf2f(x.w);
            }
        }
    }
    a0 += __shfl_xor(a0, 4); a0 += __shfl_xor(a0, 8); a0 += __shfl_xor(a0, 16); a0 += __shfl_xor(a0, 32);
    a1 += __shfl_xor(a1, 4); a1 += __shfl_xor(a1, 8); a1 += __shfl_xor(a1, 16); a1 += __shfl_xor(a1, 32);
    a2 += __shfl_xor(a2, 4); a2 += __shfl_xor(a2, 8); a2 += __shfl_xor(a2, 16); a2 += __shfl_xor(a2, 32);
    a3 += __shfl_xor(a3, 4); a3 += __shfl_xor(a3, 8); a3 += __shfl_xor(a3, 16); a3 += __shfl_xor(a3, 32);
    if (g == 0) {
        int c4 = (lane & 3) * 4;
        float dn = dinv[node];
        float v0 = alpha * dn * a0;
        float v1 = alpha * dn * a1;
        float v2 = alpha * dn * a2;
        float v3 = alpha * dn * a3;
        if (Z) {
            float4 zv = *(const float4*)&Z[(size_t)node * 16 + c4];
            v0 += beta * zv.x; v1 += beta * zv.y; v2 += beta * zv.z; v3 += beta * zv.w;
        }
        float4 r = { v0, v1, v2, v3 };
        *(float4*)&out[(size_t)node * 16 + c4] = r;
        if (outd) {
            ushort4 u = { bfb(v0 * dn), bfb(v1 * dn), bfb(v2 * dn), bfb(v3 * dn) };
            *(ushort4*)&outd[(size_t)node * 16 + c4] = u;
        }
    }
}

// ---------------- 64-dim Chebyshev aggregation, padded branch-free (R15) ----------------
// 1 wave per node. 4 independent uint4 gathers (8 rows x 128B each) cover 32 edges;
// out-of-degree lanes read the shared zero page (L1-hot, contributes 0). Z is bf16.

__global__ __launch_bounds__(256) void k_aggr64(const unsigned short* __restrict__ Xd,
                                                const unsigned short* __restrict__ Z,
                                                const float* __restrict__ dinv,
                                                const int* __restrict__ row_off, const int* __restrict__ csr,
                                                unsigned short* __restrict__ outb, unsigned short* __restrict__ outd,
                                                float alpha, float beta, int zoff, int N) {
    int node = blockIdx.x * 4 + (threadIdx.x >> 6);
    if (node >= N) return;
    int lane = threadIdx.x & 63;
    int g = lane >> 3;                  // 8 edge groups
    int co = (lane & 7) * 16;           // byte offset of this lane's 8 cols
    int beg = row_off[node], end = row_off[node + 1];
    int deg = end - beg;
    int myOff = (lane < deg) ? (csr[beg + lane] << 7) : zoff;   // 128B rows; pad -> zero page
    const char* base = (const char*)Xd + co;
    float a0 = 0.f, a1 = 0.f, a2 = 0.f, a3 = 0.f, a4 = 0.f, a5 = 0.f, a6 = 0.f, a7 = 0.f;
    {
        int o0 = __shfl(myOff, g);
        int o1 = __shfl(myOff, 8 + g);
        int o2 = __shfl(myOff, 16 + g);
        int o3 = __shfl(myOff, 24 + g);
        uint4 x0 = *(const uint4*)(base + o0);
        uint4 x1 = *(const uint4*)(base + o1);
        uint4 x2 = *(const uint4*)(base + o2);
        uint4 x3 = *(const uint4*)(base + o3);
        acc2(a0, a1, x0.x); acc2(a2, a3, x0.y); acc2(a4, a5, x0.z); acc2(a6, a7, x0.w);
        acc2(a0, a1, x1.x); acc2(a2, a3, x1.y); acc2(a4, a5, x1.z); acc2(a6, a7, x1.w);
        acc2(a0, a1, x2.x); acc2(a2, a3, x2.y); acc2(a4, a5, x2.z); acc2(a6, a7, x2.w);
        acc2(a0, a1, x3.x); acc2(a2, a3, x3.y); acc2(a4, a5, x3.z); acc2(a6, a7, x3.w);
    }
    if (deg > 32) {
        int dmain = deg < 64 ? deg : 64;
        for (int j = 32; j < dmain; j += 8) {            // shfl overshoot -> zero page
            int o = __shfl(myOff, j + g);
            uint4 x = *(const uint4*)(base + o);
            acc2(a0, a1, x.x); acc2(a2, a3, x.y); acc2(a4, a5, x.z); acc2(a6, a7, x.w);
        }
        for (int e = beg + 64; e < end; e += 8) {        // deg>64: essentially never
            int idx = e + g;
            int s = csr[idx < end ? idx : end - 1];
            uint4 x = *(const uint4*)(base + (s << 7));
            if (idx < end) {
                acc2(a0, a1, x.x); acc2(a2, a3, x.y); acc2(a4, a5, x.z); acc2(a6, a7, x.w);
            }
        }
    }
    a0 += __shfl_xor(a0, 8); a0 += __shfl_xor(a0, 16); a0 += __shfl_xor(a0, 32);
    a1 += __shfl_xor(a1, 8); a1 += __shfl_xor(a1, 16); a1 += __shfl_xor(a1, 32);
    a2 += __shfl_xor(a2, 8); a2 += __shfl_xor(a2, 16); a2 += __shfl_xor(a2, 32);
    a3 += __shfl_xor(a3, 8); a3 += __shfl_xor(a3, 16); a3 += __shfl_xor(a3, 32);
    a4 += __shfl_xor(a4, 8); a4 += __shfl_xor(a4, 16); a4 += __shfl_xor(a4, 32);
    a5 += __shfl_xor(a5, 8); a5 += __shfl_xor(a5, 16); a5 += __shfl_xor(a5, 32);
    a6 += __shfl_xor(a6, 8); a6 += __shfl_xor(a6, 16); a6 += __shfl_xor(a6, 32);
    a7 += __shfl_xor(a7, 8); a7 += __shfl_xor(a7, 16); a7 += __shfl_xor(a7, 32);
    if (g == 0) {                       // lanes 0..7 hold cols lane*8 .. lane*8+7
        float dn = dinv[node];
        float v[8] = { a0, a1, a2, a3, a4, a5, a6, a7 };
#pragma unroll
        for (int i = 0; i < 8; ++i) v[i] *= alpha * dn;
        size_t rb = (size_t)node * 128 + co;            // byte offset of this lane's span
        if (Z) {
            uint4 zv = *(const uint4*)((const char*)Z + rb);
            unsigned zd[4] = { zv.x, zv.y, zv.z, zv.w };
#pragma unroll
            for (int i = 0; i < 4; ++i) {
                union { unsigned u; float f; } lo, hi;
                lo.u = zd[i] << 16; hi.u = zd[i] & 0xffff0000u;
                v[2 * i] += beta * lo.f;
                v[2 * i + 1] += beta * hi.f;
            }
        }
        uint4 ub, ud;
        unsigned* pb = (unsigned*)&ub;
        unsigned* pd = (unsigned*)&ud;
#pragma unroll
        for (int i = 0; i < 4; ++i) {
            pb[i] = (unsigned)bfb(v[2 * i]) | ((unsigned)bfb(v[2 * i + 1]) << 16);
            pd[i] = (unsigned)bfb(v[2 * i] * dn) | ((unsigned)bfb(v[2 * i + 1] * dn) << 16);
        }
        *(uint4*)((char*)outb + rb) = ub;
        if (outd) *(uint4*)((char*)outd + rb) = ud;
    }
}

// ---------------- Cheb matmul via MFMA 16x16x32 bf16 ----------------
// BIN16: X0,X1,X2 all bf16 (layers 2/3). BOUT16: emit bf16.

template <int KDIM, bool BIN16, bool BOUT16>
__global__ __launch_bounds__(256) void k_cheb_m(const void* __restrict__ X0v, const void* __restrict__ X1v,
                                                const void* __restrict__ X2v, const float* __restrict__ W,
                                                const float* __restrict__ b, void* __restrict__ outv, int N) {
    constexpr int KT = (KDIM == 16) ? 64 : 3 * KDIM;
    constexpr int SX = KT + 8;
    __shared__ unsigned short Xs[64 * SX];
    __shared__ unsigned short Ws[64 * SX];
    int t = threadIdx.x;

    {
        int sn = t & 63;
        int gn = blockIdx.x * 64 + sn; if (gn >= N) gn = N - 1;
        int k0 = (t >> 6) * (KDIM / 4);
        if constexpr (BIN16) {
            const unsigned short* Xp[3] = { (const unsigned short*)X0v, (const unsigned short*)X1v,
                                            (const unsigned short*)X2v };
#pragma unroll
            for (int a = 0; a < 3; ++a) {
#pragma unroll
                for (int i = 0; i < KDIM / 16; ++i) {
                    *(ushort4*)&Xs[sn * SX + a * KDIM + k0 + 4 * i] =
                        *(const ushort4*)&Xp[a][(size_t)gn * KDIM + k0 + 4 * i];
                }
            }
        } else {
            const float* Xp[3] = { (const float*)X0v, (const float*)X1v, (const float*)X2v };
#pragma unroll
            for (int a = 0; a < 3; ++a) {
#pragma unroll
                for (int i = 0; i < KDIM / 16; ++i) {
                    float4 v = *(const float4*)&Xp[a][(size_t)gn * KDIM + k0 + 4 * i];
                    ushort4 u = { bfb(v.x), bfb(v.y), bfb(v.z), bfb(v.w) };
                    *(ushort4*)&Xs[sn * SX + a * KDIM + k0 + 4 * i] = u;
                }
            }
        }
        if (KDIM == 16) {
            int kp = 48 + (t >> 6) * 4;
            ushort4 z = { 0, 0, 0, 0 };
            *(ushort4*)&Xs[sn * SX + kp] = z;
        }
    }
    for (int idx = t; idx < 3 * KDIM * 64; idx += 256) {
        int a = idx / (KDIM * 64);
        int r = idx % (KDIM * 64);
        int k = r >> 6, n = r & 63;
        Ws[n * SX + a * KDIM + k] = bfb(W[idx]);
    }
    if (KDIM == 16) {
        for (int idx = t; idx < 1024; idx += 256) {
            int n = idx & 63, k = 48 + (idx >> 6);
            Ws[n * SX + k] = 0;
        }
    }
    __syncthreads();

    int wave = t >> 6, lane = t & 63;
    int fi = lane & 15, quad = lane >> 4;
    int arow = wave * 16 + fi;

    floatx4 acc0 = {0.f,0.f,0.f,0.f}, acc1 = {0.f,0.f,0.f,0.f}, acc2v = {0.f,0.f,0.f,0.f}, acc3 = {0.f,0.f,0.f,0.f};
#pragma unroll
    for (int ks = 0; ks < KT / 32; ++ks) {
        short8 af = *(const short8*)&Xs[arow * SX + ks * 32 + quad * 8];
        short8 b0 = *(const short8*)&Ws[(0 * 16 + fi) * SX + ks * 32 + quad * 8];
        short8 b1 = *(const short8*)&Ws[(1 * 16 + fi) * SX + ks * 32 + quad * 8];
        short8 b2 = *(const short8*)&Ws[(2 * 16 + fi) * SX + ks * 32 + quad * 8];
        short8 b3 = *(const short8*)&Ws[(3 * 16 + fi) * SX + ks * 32 + quad * 8];
        acc0 = __builtin_amdgcn_mfma_f32_16x16x32_bf16(af, b0, acc0, 0, 0, 0);
        acc1 = __builtin_amdgcn_mfma_f32_16x16x32_bf16(af, b1, acc1, 0, 0, 0);
        acc2v = __builtin_amdgcn_mfma_f32_16x16x32_bf16(af, b2, acc2v, 0, 0, 0);
        acc3 = __builtin_amdgcn_mfma_f32_16x16x32_bf16(af, b3, acc3, 0, 0, 0);
    }

    int nbase = blockIdx.x * 64 + wave * 16 + quad * 4;
    floatx4 accs[4] = { acc0, acc1, acc2v, acc3 };
#pragma unroll
    for (int nt = 0; nt < 4; ++nt) {
        int col = nt * 16 + fi;
        float bias = b[col];
#pragma unroll
        for (int reg = 0; reg < 4; ++reg) {
            int node = nbase + reg;
            if (node < N) {
                float r = fmaxf(accs[nt][reg] + bias, 0.f);
                if constexpr (BOUT16) {
                    ((unsigned short*)outv)[(size_t)node * 64 + col] = bfb(r);
                } else {
                    ((float*)outv)[(size_t)node * 64 + col] = r;
                }
            }
        }
    }
}

// ---------------- EdgeConv stage 1 via MFMA: [m|p] = X @ [Wt | Wt+Wp] ----------------
// md stores ORDER-KEYS of (-theta); consumer does packed u16 max.

__global__ __launch_bounds__(256) void k_e1_m(const unsigned short* X, const float* __restrict__ Wt,
                                              const float* __restrict__ Wp, const float* __restrict__ bt,
                                              const float* __restrict__ bp,
                                              unsigned short* md, float* __restrict__ pbuf, int N) {
    constexpr int SX = 72;
    __shared__ unsigned short Xs[64 * SX];
    __shared__ unsigned short Ws[128 * SX];
    int t = threadIdx.x;

    {
        int sn = t & 63;
        int gn = blockIdx.x * 64 + sn; if (gn >= N) gn = N - 1;
        int k0 = (t >> 6) * 16;
#pragma unroll
        for (int i = 0; i < 2; ++i) {
            *(short8*)&Xs[sn * SX + k0 + 8 * i] = *(const short8*)&X[(size_t)gn * 64 + k0 + 8 * i];
        }
    }
    for (int idx = t; idx < 4096; idx += 256) {
        int k = idx >> 6, n = idx & 63;
        float wt = Wt[idx];
        Ws[n * SX + k] = bfb(wt);
        Ws[(64 + n) * SX + k] = bfb(wt + Wp[idx]);
    }
    __syncthreads();

    int wave = t >> 6, lane = t & 63;
    int fi = lane & 15, quad = lane >> 4;
    int arow = wave * 16 + fi;

    floatx4 acc[8];
#pragma unroll
    for (int i = 0; i < 8; ++i) acc[i] = (floatx4){0.f,0.f,0.f,0.f};
#pragma unroll
    for (int ks = 0; ks < 2; ++ks) {
        short8 af = *(const short8*)&Xs[arow * SX + ks * 32 + quad * 8];
#pragma unroll
        for (int nt = 0; nt < 8; ++nt) {
            short8 bf = *(const short8*)&Ws[(nt * 16 + fi) * SX + ks * 32 + quad * 8];
            acc[nt] = __builtin_amdgcn_mfma_f32_16x16x32_bf16(af, bf, acc[nt], 0, 0, 0);
        }
    }

    int nbase = blockIdx.x * 64 + wave * 16 + quad * 4;
#pragma unroll
    for (int nt = 0; nt < 8; ++nt) {
        int col = nt * 16 + fi;
        if (col < 64) {
#pragma unroll
            for (int reg = 0; reg < 4; ++reg) {
                int node = nbase + reg;
                if (node < N) {
                    unsigned u = (unsigned)bfb(acc[nt][reg]) ^ 0x8000u;
                    unsigned key = (u & 0x8000u) ? (~u & 0xffffu) : (u | 0x8000u);
                    md[(size_t)node * 64 + col] = (unsigned short)key;
                }
            }
        } else {
            int cc = col - 64;
            float bias = bt[cc] + bp[cc];
#pragma unroll
            for (int reg = 0; reg < 4; ++reg) {
                int node = nbase + reg;
                if (node < N) pbuf[(size_t)node * 64 + cc] = acc[nt][reg] + bias;
            }
        }
    }
}

// ---------------- EdgeConv stage 2: padded branch-free packed key-max (R15) ----------------
// Clamp-to-last-edge padding (idempotent for max). 4 independent uint4 gathers.
// out is bf16 (consumers convert anyway).

__global__ __launch_bounds__(256) void k_e2_b(const unsigned short* __restrict__ md, const float* __restrict__ pbuf,
                                              const int* __restrict__ row_off, const int* __restrict__ csr,
                                              const float* __restrict__ dinv, unsigned short* __restrict__ out,
                                              unsigned short* __restrict__ outd, int zoff, int N) {
    int node = blockIdx.x * 4 + (threadIdx.x >> 6);
    if (node >= N) return;
    int lane = threadIdx.x & 63;
    int g = lane >> 3;                  // 8 edge groups
    int co = (lane & 7) * 16;           // byte offset of this lane's 8 cols
    int beg = row_off[node], end = row_off[node + 1];
    int deg = end - beg;
    int dmain = deg < 64 ? deg : 64;
    int li = lane < dmain ? lane : dmain - 1;            // clamp (dup last edge)
    int myOff = (deg > 0) ? (csr[beg + li] << 7) : zoff; // deg==0 -> zero page (unused)
    const char* base = (const char*)md + co;
    unsigned k0 = 0, k1 = 0, k2 = 0, k3 = 0;             // 0 <= every real key
    {
        int o0 = __shfl(myOff, g);
        int o1 = __shfl(myOff, 8 + g);
        int o2 = __shfl(myOff, 16 + g);
        int o3 = __shfl(myOff, 24 + g);
        uint4 x0 = *(const uint4*)(base + o0);
        uint4 x1 = *(const uint4*)(base + o1);
        uint4 x2 = *(const uint4*)(base + o2);
        uint4 x3 = *(const uint4*)(base + o3);
        k0 = pkmaxu16(k0, x0.x); k1 = pkmaxu16(k1, x0.y); k2 = pkmaxu16(k2, x0.z); k3 = pkmaxu16(k3, x0.w);
        k0 = pkmaxu16(k0, x1.x); k1 = pkmaxu16(k1, x1.y); k2 = pkmaxu16(k2, x1.z); k3 = pkmaxu16(k3, x1.w);
        k0 = pkmaxu16(k0, x2.x); k1 = pkmaxu16(k1, x2.y); k2 = pkmaxu16(k2, x2.z); k3 = pkmaxu16(k3, x2.w);
        k0 = pkmaxu16(k0, x3.x); k1 = pkmaxu16(k1, x3.y); k2 = pkmaxu16(k2, x3.z); k3 = pkmaxu16(k3, x3.w);
    }
    if (deg > 32) {
        for (int j = 32; j < dmain; j += 8) {            // shfl overshoot -> dup last
            int o = __shfl(myOff, j + g);
            uint4 x = *(const uint4*)(base + o);
            k0 = pkmaxu16(k0, x.x); k1 = pkmaxu16(k1, x.y); k2 = pkmaxu16(k2, x.z); k3 = pkmaxu16(k3, x.w);
        }
        for (int e = beg + 64; e < end; e += 8) {        // deg>64: essentially never
            int idx = e + g;
            int s = csr[idx < end ? idx : end - 1];      // clamp dup (idempotent)
            uint4 x = *(const uint4*)(base + (s << 7));
            k0 = pkmaxu16(k0, x.x); k1 = pkmaxu16(k1, x.y); k2 = pkmaxu16(k2, x.z); k3 = pkmaxu16(k3, x.w);
        }
    }
    k0 = pkmaxu16(k0, __shfl_xor((int)k0, 8)); k0 = pkmaxu16(k0, __shfl_xor((int)k0, 16)); k0 = pkmaxu16(k0, __shfl_xor((int)k0, 32));
    k1 = pkmaxu16(k1, __shfl_xor((int)k1, 8)); k1 = pkmaxu16(k1, __shfl_xor((int)k1, 16)); k1 = pkmaxu16(k1, __shfl_xor((int)k1, 32));
    k2 = pkmaxu16(k2, __shfl_xor((int)k2, 8)); k2 = pkmaxu16(k2, __shfl_xor((int)k2, 16)); k2 = pkmaxu16(k2, __shfl_xor((int)k2, 32));
    k3 = pkmaxu16(k3, __shfl_xor((int)k3, 8)); k3 = pkmaxu16(k3, __shfl_xor((int)k3, 16)); k3 = pkmaxu16(k3, __shfl_xor((int)k3, 32));
    if (g == 0) {                       // lanes 0..7 hold cols lane*8 .. lane*8+7
        unsigned kd[4] = { k0, k1, k2, k3 };
        float a[8];
#pragma unroll
        for (int i = 0; i < 4; ++i) {
            unsigned klo = kd[i] & 0xffffu, khi = kd[i] >> 16;
            unsigned short tlo = (klo & 0x8000u) ? (unsigned short)(klo & 0x7fffu) : (unsigned short)(~klo & 0xffffu);
            unsigned short thi = (khi & 0x8000u) ? (unsigned short)(khi & 0x7fffu) : (unsigned short)(~khi & 0xffffu);
            a[2 * i] = bf2f(tlo);
            a[2 * i + 1] = bf2f(thi);
        }
        float r[8];
        if (end > beg) {
            const float* pv = &pbuf[(size_t)node * 64 + (lane & 7) * 8];
            float4 p0 = *(const float4*)pv;
            float4 p1 = *(const float4*)(pv + 4);
            r[0] = fmaxf(p0.x + a[0], 0.f); r[1] = fmaxf(p0.y + a[1], 0.f);
            r[2] = fmaxf(p0.z + a[2], 0.f); r[3] = fmaxf(p0.w + a[3], 0.f);
            r[4] = fmaxf(p1.x + a[4], 0.f); r[5] = fmaxf(p1.y + a[5], 0.f);
            r[6] = fmaxf(p1.z + a[6], 0.f); r[7] = fmaxf(p1.w + a[7], 0.f);
        } else {
#pragma unroll
            for (int i = 0; i < 8; ++i) r[i] = 0.f;
        }
        float dn = dinv[node];
        size_t rb = (size_t)node * 128 + co;
        uint4 ub, ud;
        unsigned* pb = (unsigned*)&ub;
        unsigned* pd = (unsigned*)&ud;
#pragma unroll
        for (int i = 0; i < 4; ++i) {
            pb[i] = (unsigned)bfb(r[2 * i]) | ((unsigned)bfb(r[2 * i + 1]) << 16);
            pd[i] = (unsigned)bfb(r[2 * i] * dn) | ((unsigned)bfb(r[2 * i + 1] * dn) << 16);
        }
        *(uint4*)((char*)out + rb) = ub;
        *(uint4*)((char*)outd + rb) = ud;
    }
}

// ---------------- graph mean pooling (segmented: gid is sorted) ----------------

__global__ __launch_bounds__(256) void k_pool(const float* __restrict__ h, const int* __restrict__ gid,
                                              float* __restrict__ out, float* __restrict__ gcnt, int N) {
    const int CHUNK = 128;
    int wave = blockIdx.x * 4 + (threadIdx.x >> 6);
    int lane = threadIdx.x & 63;
    int beg = wave * CHUNK;
    if (beg >= N) return;
    int end = beg + CHUNK < N ? beg + CHUNK : N;
    int gcur = gid[beg];
    float acc = 0.f;
    int cnt = 0;
    for (int n = beg; n < end; ++n) {
        int g = gid[n];
        float v = h[n * 64 + lane];
        if (g != gcur) {
            atomicAdd(&out[gcur * 64 + lane], acc);
            if (lane == 0) atomicAdd(&gcnt[gcur], (float)cnt);
            gcur = g; acc = 0.f; cnt = 0;
        }
        acc += v;
        ++cnt;
    }
    atomicAdd(&out[gcur * 64 + lane], acc);
    if (lane == 0) atomicAdd(&gcnt[gcur], (float)cnt);
}

__global__ __launch_bounds__(256) void k_div(float* __restrict__ out, const float* __restrict__ gcnt, int total) {
    int i = blockIdx.x * blockDim.x + threadIdx.x;
    if (i < total) out[i] /= fmaxf(gcnt[i >> 6], 1.f);
}

// ---------------- launcher ----------------

extern "C" void kernel_launch(void* const* d_in, const int* in_sizes, int n_in,
                              void* d_out, int out_size, void* d_ws, size_t ws_size,
                              hipStream_t stream) {
    const float* feat = (const float*)d_in[0];
    const int* src = (const int*)d_in[1];
    const int* dst = (const int*)d_in[2];
    const int* gid = (const int*)d_in[3];
    const float* W1 = (const float*)d_in[4];  const float* b1 = (const float*)d_in[5];
    const float* W2 = (const float*)d_in[6];  const float* b2 = (const float*)d_in[7];
    const float* W3 = (const float*)d_in[8];  const float* b3 = (const float*)d_in[9];
    const float* Wt1 = (const float*)d_in[10]; const float* bt1 = (const float*)d_in[11];
    const float* Wp1 = (const float*)d_in[12]; const float* bp1 = (const float*)d_in[13];
    const float* Wt2 = (const float*)d_in[14]; const float* bt2 = (const float*)d_in[15];
    const float* Wp2 = (const float*)d_in[16]; const float* bp2 = (const float*)d_in[17];
    float* out = (float*)d_out;

    const int N = in_sizes[0] / 16;
    const int E = in_sizes[1];
    const int G = out_size / 64;
    const int nb = (N + 255) >> 8;      // buckets (<= 512)

    char* p = (char*)d_ws;
    auto alloc = [&](size_t nbytes) {
        void* r = (void*)p;
        p += (nbytes + 255) & ~(size_t)255;
        return r;
    };
    int* row_off  = (int*)alloc((size_t)(N + 1) * 4);
    int* csr      = (int*)alloc((size_t)E * 4);
    int* bcnt     = (int*)alloc(512 * 4);
    int* boff     = (int*)alloc(513 * 4);
    int* bcur     = (int*)alloc(512 * 4);
    float* dinv   = (float*)alloc((size_t)N * 4);
    char* zpage   = (char*)alloc(256);          // shared zero page for gather padding
    float* bufA   = (float*)alloc((size_t)N * 64 * 4);
    float* bufB   = (float*)alloc((size_t)N * 64 * 4);
    float* bufC   = (float*)alloc((size_t)N * 64 * 4);
    float* bufD   = (float*)alloc((size_t)N * 64 * 4);
    unsigned short* md = (unsigned short*)alloc((size_t)N * 64 * 2);
    float* gcnt   = (float*)alloc((size_t)G * 4);

    unsigned* ebuf = (unsigned*)bufA;   // alias: bufA dead until after CSR build
    unsigned short* hd = (unsigned short*)bufC;
    unsigned short* xd = (unsigned short*)bufC + (size_t)N * 64;
    unsigned short* hb = md;            // cheb bf16 output; block-local r/w in k_e1_m is safe
    unsigned short* hD = (unsigned short*)bufD;  // e2 bf16 output (unscaled)

    const int zo_hd = (int)((char*)zpage - (char*)hd);
    const int zo_xd = (int)((char*)zpage - (char*)xd);
    const int zo_md = (int)((char*)zpage - (char*)md);

    hipMemsetAsync(bcnt, 0, 512 * 4, stream);
    hipMemsetAsync(zpage, 0, 256, stream);
    hipMemsetAsync(gcnt, 0, (size_t)G * 4, stream);
    hipMemsetAsync(d_out, 0, (size_t)out_size * 4, stream);

    const int nb16 = (N * 16 + 255) / 256;
    const int nbw = (N + 3) / 4;
    const int npool = ((N + 127) / 128 + 3) / 4;
    const int nbt = (N + 63) / 64;
    const int npart = (E + PCHUNK - 1) / PCHUNK;

    // ---- bucketed CSR build v3 (4 launches)
    k_bhist<<<256, 256, 0, stream>>>(dst, bcnt, E);
    k_scanBkt<<<1, 512, 0, stream>>>(bcnt, boff, bcur, nb, E);
    k_partA<<<npart, 256, 0, stream>>>(src, dst, bcur, ebuf, E);
    k_finish<<<nb, 256, 0, stream>>>(ebuf, boff, row_off, dinv, csr, N, E);

    // ---- Cheb layer 1 (IN=16)
    k_feat16<<<nb16, 256, 0, stream>>>(feat, dinv, hd, N * 16);
    k_aggr16<<<nbw, 256, 0, stream>>>(hd, nullptr, dinv, row_off, csr, bufA, xd, -1.f, 0.f, zo_hd, N);
    k_aggr16<<<nbw, 256, 0, stream>>>(xd, feat, dinv, row_off, csr, bufB, nullptr, -2.f, -1.f, zo_xd, N);
    k_cheb_m<16, false, true><<<nbt, 256, 0, stream>>>(feat, bufA, bufB, W1, b1, hb, N);

    // ---- EdgeConv 1
    k_e1_m<<<nbt, 256, 0, stream>>>(hb, Wt1, Wp1, bt1, bp1, md, bufB, N);
    k_e2_b<<<nbw, 256, 0, stream>>>(md, bufB, row_off, csr, dinv, hD, hd, zo_md, N);

    // ---- Cheb layer 2
    k_aggr64<<<nbw, 256, 0, stream>>>(hd, nullptr, dinv, row_off, csr, (unsigned short*)bufA, xd, -1.f, 0.f, zo_hd, N);
    k_aggr64<<<nbw, 256, 0, stream>>>(xd, hD, dinv, row_off, csr, (unsigned short*)bufB, nullptr, -2.f, -1.f, zo_xd, N);
    k_cheb_m<64, true, true><<<nbt, 256, 0, stream>>>(hD, bufA, bufB, W2, b2, hb, N);

    // ---- EdgeConv 2
    k_e1_m<<<nbt, 256, 0, stream>>>(hb, Wt2, Wp2, bt2, bp2, md, bufB, N);
    k_e2_b<<<nbw, 256, 0, stream>>>(md, bufB, row_off, csr, dinv, hD, hd, zo_md, N);

    // ---- Cheb layer 3 (fp32 out -> pooling)
    k_aggr64<<<nbw, 256, 0, stream>>>(hd, nullptr, dinv, row_off, csr, (unsigned short*)bufA, xd, -1.f, 0.f, zo_hd, N);
    k_aggr64<<<nbw, 256, 0, stream>>>(xd, hD, dinv, row_off, csr, (unsigned short*)bufB, nullptr, -2.f, -1.f, zo_xd, N);
    k_cheb_m<64, true, false><<<nbt, 256, 0, stream>>>(hD, bufA, bufB, W3, b3, bufC, N);

    // ---- per-graph mean pooling
    k_pool<<<npool, 256, 0, stream>>>(bufC, gid, out, gcnt, N);
    k_div<<<(out_size + 255) / 256, 256, 0, stream>>>(out, gcnt, out_size);
}

// Round 4
// 568.347 us; speedup vs baseline: 1.0932x; 1.0472x over previous
//
#include <hip/hip_runtime.h>
#include <hip/hip_bf16.h>
#include <math.h>

typedef __attribute__((ext_vector_type(8))) short short8;
typedef __attribute__((ext_vector_type(4))) float floatx4;

__device__ __forceinline__ unsigned short bfb(float x) {
    union { __hip_bfloat16 h; unsigned short u; } c;
    c.h = __float2bfloat16(x);
    return c.u;
}
__device__ __forceinline__ float bf2f(unsigned short u) {
    union { unsigned int i; float f; } c;
    c.i = ((unsigned int)u) << 16;
    return c.f;
}
// accumulate the two bf16 halves of a dword into two f32 accumulators
__device__ __forceinline__ void acc2(float& lo, float& hi, unsigned d) {
    union { unsigned u; float f; } a, b;
    a.u = d << 16;
    b.u = d & 0xffff0000u;
    lo += a.f; hi += b.f;
}
// packed unsigned 16-bit max (gfx9 VOP3P, inherited on CDNA4)
__device__ __forceinline__ unsigned pkmaxu16(unsigned a, unsigned b) {
    unsigned d;
    asm("v_pk_max_u16 %0, %1, %2" : "=v"(d) : "v"(a), "v"(b));
    return d;
}

// ---------------- bucketed CSR build v3 ----------------

__global__ __launch_bounds__(256) void k_bhist(const int* __restrict__ dst, int* __restrict__ bcnt, int E) {
    __shared__ int h[512];
    int t = threadIdx.x;
    for (int i = t; i < 512; i += 256) h[i] = 0;
    __syncthreads();
    int step = gridDim.x * 256;
    for (int i = blockIdx.x * 256 + t; i < E; i += step) atomicAdd(&h[dst[i] >> 8], 1);
    __syncthreads();
    for (int i = t; i < 512; i += 256) if (h[i]) atomicAdd(&bcnt[i], h[i]);
}

__global__ __launch_bounds__(512) void k_scanBkt(const int* __restrict__ bcnt, int* __restrict__ boff,
                                                 int* __restrict__ bcur, int nb, int E) {
    __shared__ int s[512];
    int t = threadIdx.x;
    int v = (t < nb) ? bcnt[t] : 0;
    s[t] = v;
    __syncthreads();
    for (int off = 1; off < 512; off <<= 1) {
        int x = (t >= off) ? s[t - off] : 0;
        __syncthreads();
        s[t] += x;
        __syncthreads();
    }
    if (t < nb) { boff[t] = s[t] - v; bcur[t] = s[t] - v; }
    if (t == 0) boff[nb] = E;
}

#define PCHUNK 8192

__global__ __launch_bounds__(256) void k_partA(const int* __restrict__ src, const int* __restrict__ dst,
                                               int* __restrict__ bcur, unsigned* __restrict__ ebuf, int E) {
    __shared__ int h[512];
    __shared__ int base[512];
    int t = threadIdx.x;
    for (int i = t; i < 512; i += 256) h[i] = 0;
    __syncthreads();
    int start = blockIdx.x * PCHUNK;
    int end = start + PCHUNK < E ? start + PCHUNK : E;
    for (int i = start + t; i < end; i += 256) atomicAdd(&h[dst[i] >> 8], 1);
    __syncthreads();
    for (int i = t; i < 512; i += 256) {
        int c = h[i];
        base[i] = c ? atomicAdd(&bcur[i], c) : 0;
        h[i] = 0;
    }
    __syncthreads();
    for (int i = start + t; i < end; i += 256) {
        int d = dst[i];
        int b = d >> 8;
        int r = atomicAdd(&h[b], 1);
        ebuf[base[b] + r] = ((unsigned)src[i] << 8) | (unsigned)(d & 255);
    }
}

__global__ __launch_bounds__(256) void k_finish(const unsigned* __restrict__ ebuf, const int* __restrict__ boff,
                                                int* __restrict__ row_off, float* __restrict__ dinv,
                                                float* __restrict__ dsq, int* __restrict__ csr, int N, int E) {
    __shared__ int h[256];
    __shared__ int sc[256];
    __shared__ int cur[256];
    int b = blockIdx.x, t = threadIdx.x;
    h[t] = 0;
    __syncthreads();
    int beg = boff[b], end = boff[b + 1];
    for (int e = beg + t; e < end; e += 256) atomicAdd(&h[ebuf[e] & 255], 1);
    __syncthreads();
    int v = h[t];
    sc[t] = v;
    __syncthreads();
    for (int off = 1; off < 256; off <<= 1) {
        int x = (t >= off) ? sc[t - off] : 0;
        __syncthreads();
        sc[t] += x;
        __syncthreads();
    }
    int node = (b << 8) + t;
    int excl = beg + sc[t] - v;
    if (node < N) {
        row_off[node] = excl;
        float dg = (float)(v > 1 ? v : 1);
        dinv[node] = rsqrtf(dg);
        dsq[node] = sqrtf(dg);
    }
    cur[t] = excl;
    if (b == 0 && t == 0) row_off[N] = E;
    __syncthreads();
    for (int e = beg + t; e < end; e += 256) {
        unsigned ed = ebuf[e];
        int pos = atomicAdd(&cur[ed & 255], 1);
        csr[pos] = (int)(ed >> 8);
    }
}

// ---------------- feat -> bf16 pre-scaled ----------------

__global__ __launch_bounds__(256) void k_feat16(const float* __restrict__ feat, const float* __restrict__ dinv,
                                                unsigned short* __restrict__ featd, int total) {
    int i = blockIdx.x * 256 + threadIdx.x;
    if (i < total) featd[i] = bfb(feat[i] * dinv[i >> 4]);
}

// ---------------- 16-dim Chebyshev aggregation, padded branch-free ----------------

__global__ __launch_bounds__(256) void k_aggr16(const unsigned short* __restrict__ Xd, const float* __restrict__ Z,
                                                const float* __restrict__ dinv,
                                                const int* __restrict__ row_off, const int* __restrict__ csr,
                                                float* __restrict__ out, unsigned short* __restrict__ outd,
                                                float alpha, float beta, int zoff, int N) {
    int node = blockIdx.x * 4 + (threadIdx.x >> 6);
    if (node >= N) return;
    int lane = threadIdx.x & 63;
    int g = lane >> 2;                  // 16 edge groups
    int co = (lane & 3) * 8;            // byte offset of this lane's 4 cols
    int beg = row_off[node], end = row_off[node + 1];
    int deg = end - beg;
    int myOff = (lane < deg) ? (csr[beg + lane] << 5) : zoff;   // 32B rows; pad -> zero page
    const char* base = (const char*)Xd + co;
    float a0 = 0.f, a1 = 0.f, a2 = 0.f, a3 = 0.f;
    {
        int o0 = __shfl(myOff, g);
        int o1 = __shfl(myOff, 16 + g);
        ushort4 x0 = *(const ushort4*)(base + o0);
        ushort4 x1 = *(const ushort4*)(base + o1);
        a0 += bf2f(x0.x); a1 += bf2f(x0.y); a2 += bf2f(x0.z); a3 += bf2f(x0.w);
        a0 += bf2f(x1.x); a1 += bf2f(x1.y); a2 += bf2f(x1.z); a3 += bf2f(x1.w);
    }
    if (deg > 32) {
        int dmain = deg < 64 ? deg : 64;
        for (int j = 32; j < dmain; j += 16) {           // shfl overshoot -> zero page
            int o = __shfl(myOff, j + g);
            ushort4 x = *(const ushort4*)(base + o);
            a0 += bf2f(x.x); a1 += bf2f(x.y); a2 += bf2f(x.z); a3 += bf2f(x.w);
        }
        for (int e = beg + 64; e < end; e += 16) {       // deg>64: essentially never
            int idx = e + g;
            int s = csr[idx < end ? idx : end - 1];
            ushort4 x = *(const ushort4*)(base + (s << 5));
            if (idx < end) {
                a0 += bf2f(x.x); a1 += bf2f(x.y); a2 += bf2f(x.z); a3 += bf2f(x.w);
            }
        }
    }
    a0 += __shfl_xor(a0, 4); a0 += __shfl_xor(a0, 8); a0 += __shfl_xor(a0, 16); a0 += __shfl_xor(a0, 32);
    a1 += __shfl_xor(a1, 4); a1 += __shfl_xor(a1, 8); a1 += __shfl_xor(a1, 16); a1 += __shfl_xor(a1, 32);
    a2 += __shfl_xor(a2, 4); a2 += __shfl_xor(a2, 8); a2 += __shfl_xor(a2, 16); a2 += __shfl_xor(a2, 32);
    a3 += __shfl_xor(a3, 4); a3 += __shfl_xor(a3, 8); a3 += __shfl_xor(a3, 16); a3 += __shfl_xor(a3, 32);
    if (g == 0) {
        int c4 = (lane & 3) * 4;
        float dn = dinv[node];
        float v0 = alpha * dn * a0;
        float v1 = alpha * dn * a1;
        float v2 = alpha * dn * a2;
        float v3 = alpha * dn * a3;
        if (Z) {
            float4 zv = *(const float4*)&Z[(size_t)node * 16 + c4];
            v0 += beta * zv.x; v1 += beta * zv.y; v2 += beta * zv.z; v3 += beta * zv.w;
        }
        float4 r = { v0, v1, v2, v3 };
        *(float4*)&out[(size_t)node * 16 + c4] = r;
        if (outd) {
            ushort4 u = { bfb(v0 * dn), bfb(v1 * dn), bfb(v2 * dn), bfb(v3 * dn) };
            *(ushort4*)&outd[(size_t)node * 16 + c4] = u;
        }
    }
}

// ---------------- 64-dim Chebyshev aggregation, padded branch-free ----------------
// outb optional (R16: X1 pass writes only the dinv-scaled copy; cheb rescales).

__global__ __launch_bounds__(256) void k_aggr64(const unsigned short* __restrict__ Xd,
                                                const unsigned short* __restrict__ Z,
                                                const float* __restrict__ dinv,
                                                const int* __restrict__ row_off, const int* __restrict__ csr,
                                                unsigned short* __restrict__ outb, unsigned short* __restrict__ outd,
                                                float alpha, float beta, int zoff, int N) {
    int node = blockIdx.x * 4 + (threadIdx.x >> 6);
    if (node >= N) return;
    int lane = threadIdx.x & 63;
    int g = lane >> 3;                  // 8 edge groups
    int co = (lane & 7) * 16;           // byte offset of this lane's 8 cols
    int beg = row_off[node], end = row_off[node + 1];
    int deg = end - beg;
    int myOff = (lane < deg) ? (csr[beg + lane] << 7) : zoff;   // 128B rows; pad -> zero page
    const char* base = (const char*)Xd + co;
    float a0 = 0.f, a1 = 0.f, a2 = 0.f, a3 = 0.f, a4 = 0.f, a5 = 0.f, a6 = 0.f, a7 = 0.f;
    {
        int o0 = __shfl(myOff, g);
        int o1 = __shfl(myOff, 8 + g);
        int o2 = __shfl(myOff, 16 + g);
        int o3 = __shfl(myOff, 24 + g);
        uint4 x0 = *(const uint4*)(base + o0);
        uint4 x1 = *(const uint4*)(base + o1);
        uint4 x2 = *(const uint4*)(base + o2);
        uint4 x3 = *(const uint4*)(base + o3);
        acc2(a0, a1, x0.x); acc2(a2, a3, x0.y); acc2(a4, a5, x0.z); acc2(a6, a7, x0.w);
        acc2(a0, a1, x1.x); acc2(a2, a3, x1.y); acc2(a4, a5, x1.z); acc2(a6, a7, x1.w);
        acc2(a0, a1, x2.x); acc2(a2, a3, x2.y); acc2(a4, a5, x2.z); acc2(a6, a7, x2.w);
        acc2(a0, a1, x3.x); acc2(a2, a3, x3.y); acc2(a4, a5, x3.z); acc2(a6, a7, x3.w);
    }
    if (deg > 32) {
        int dmain = deg < 64 ? deg : 64;
        for (int j = 32; j < dmain; j += 8) {            // shfl overshoot -> zero page
            int o = __shfl(myOff, j + g);
            uint4 x = *(const uint4*)(base + o);
            acc2(a0, a1, x.x); acc2(a2, a3, x.y); acc2(a4, a5, x.z); acc2(a6, a7, x.w);
        }
        for (int e = beg + 64; e < end; e += 8) {        // deg>64: essentially never
            int idx = e + g;
            int s = csr[idx < end ? idx : end - 1];
            uint4 x = *(const uint4*)(base + (s << 7));
            if (idx < end) {
                acc2(a0, a1, x.x); acc2(a2, a3, x.y); acc2(a4, a5, x.z); acc2(a6, a7, x.w);
            }
        }
    }
    a0 += __shfl_xor(a0, 8); a0 += __shfl_xor(a0, 16); a0 += __shfl_xor(a0, 32);
    a1 += __shfl_xor(a1, 8); a1 += __shfl_xor(a1, 16); a1 += __shfl_xor(a1, 32);
    a2 += __shfl_xor(a2, 8); a2 += __shfl_xor(a2, 16); a2 += __shfl_xor(a2, 32);
    a3 += __shfl_xor(a3, 8); a3 += __shfl_xor(a3, 16); a3 += __shfl_xor(a3, 32);
    a4 += __shfl_xor(a4, 8); a4 += __shfl_xor(a4, 16); a4 += __shfl_xor(a4, 32);
    a5 += __shfl_xor(a5, 8); a5 += __shfl_xor(a5, 16); a5 += __shfl_xor(a5, 32);
    a6 += __shfl_xor(a6, 8); a6 += __shfl_xor(a6, 16); a6 += __shfl_xor(a6, 32);
    a7 += __shfl_xor(a7, 8); a7 += __shfl_xor(a7, 16); a7 += __shfl_xor(a7, 32);
    if (g == 0) {                       // lanes 0..7 hold cols lane*8 .. lane*8+7
        float dn = dinv[node];
        float v[8] = { a0, a1, a2, a3, a4, a5, a6, a7 };
#pragma unroll
        for (int i = 0; i < 8; ++i) v[i] *= alpha * dn;
        size_t rb = (size_t)node * 128 + co;            // byte offset of this lane's span
        if (Z) {
            uint4 zv = *(const uint4*)((const char*)Z + rb);
            unsigned zd[4] = { zv.x, zv.y, zv.z, zv.w };
#pragma unroll
            for (int i = 0; i < 4; ++i) {
                union { unsigned u; float f; } lo, hi;
                lo.u = zd[i] << 16; hi.u = zd[i] & 0xffff0000u;
                v[2 * i] += beta * lo.f;
                v[2 * i + 1] += beta * hi.f;
            }
        }
        if (outb) {
            uint4 ub;
            unsigned* pb = (unsigned*)&ub;
#pragma unroll
            for (int i = 0; i < 4; ++i)
                pb[i] = (unsigned)bfb(v[2 * i]) | ((unsigned)bfb(v[2 * i + 1]) << 16);
            *(uint4*)((char*)outb + rb) = ub;
        }
        if (outd) {
            uint4 ud;
            unsigned* pd = (unsigned*)&ud;
#pragma unroll
            for (int i = 0; i < 4; ++i)
                pd[i] = (unsigned)bfb(v[2 * i] * dn) | ((unsigned)bfb(v[2 * i + 1] * dn) << 16);
            *(uint4*)((char*)outd + rb) = ud;
        }
    }
}

// ---------------- fused Cheb matmul (+ optional EdgeConv stage 1) via MFMA ----------------
// BIN16: X0,X2 bf16; X1 = xd (dinv-scaled bf16) -> mid-K-segment accumulated separately
// and row-scaled by dsq[node] at epilogue (per-row scale commutes with K-sum).
// FUSE_E1: cheb ReLU output -> LDS -> e1 MFMA [m|p] = H @ [Wt | Wt+Wp]; emits md keys + bf16 pbuf.

template <int KDIM, bool BIN16, bool FUSE_E1>
__global__ __launch_bounds__(256) void k_cheb(const void* __restrict__ X0v, const void* __restrict__ X1v,
                                              const void* __restrict__ X2v, const float* __restrict__ dsq,
                                              const float* __restrict__ W, const float* __restrict__ b,
                                              const float* __restrict__ Wt, const float* __restrict__ Wp,
                                              const float* __restrict__ bt, const float* __restrict__ bp,
                                              unsigned short* __restrict__ md, unsigned short* __restrict__ pbuf,
                                              float* __restrict__ outv, int N) {
    constexpr int KT = (KDIM == 16) ? 64 : 3 * KDIM;
    constexpr int SX = KT + 8;
    constexpr int PH1 = 2 * 64 * SX;
    constexpr int PH2 = FUSE_E1 ? (64 * 72 + 128 * 72) : 0;
    constexpr int SSZ = PH1 > PH2 ? PH1 : PH2;
    __shared__ unsigned short S[SSZ];
    unsigned short* Xs = S;
    unsigned short* Ws = S + 64 * SX;
    int t = threadIdx.x;

    {
        int sn = t & 63;
        int gn = blockIdx.x * 64 + sn; if (gn >= N) gn = N - 1;
        int k0 = (t >> 6) * (KDIM / 4);
        if constexpr (BIN16) {
            const unsigned short* Xp[3] = { (const unsigned short*)X0v, (const unsigned short*)X1v,
                                            (const unsigned short*)X2v };
#pragma unroll
            for (int a = 0; a < 3; ++a) {
#pragma unroll
                for (int i = 0; i < KDIM / 16; ++i) {
                    *(ushort4*)&Xs[sn * SX + a * KDIM + k0 + 4 * i] =
                        *(const ushort4*)&Xp[a][(size_t)gn * KDIM + k0 + 4 * i];
                }
            }
        } else {
            const float* Xp[3] = { (const float*)X0v, (const float*)X1v, (const float*)X2v };
#pragma unroll
            for (int a = 0; a < 3; ++a) {
#pragma unroll
                for (int i = 0; i < KDIM / 16; ++i) {
                    float4 v = *(const float4*)&Xp[a][(size_t)gn * KDIM + k0 + 4 * i];
                    ushort4 u = { bfb(v.x), bfb(v.y), bfb(v.z), bfb(v.w) };
                    *(ushort4*)&Xs[sn * SX + a * KDIM + k0 + 4 * i] = u;
                }
            }
        }
        if constexpr (KDIM == 16) {
            int kp = 48 + (t >> 6) * 4;
            ushort4 z = { 0, 0, 0, 0 };
            *(ushort4*)&Xs[sn * SX + kp] = z;
        }
    }
    for (int idx = t; idx < 3 * KDIM * 64; idx += 256) {
        int a = idx / (KDIM * 64);
        int r = idx % (KDIM * 64);
        int k = r >> 6, n = r & 63;
        Ws[n * SX + a * KDIM + k] = bfb(W[idx]);
    }
    if constexpr (KDIM == 16) {
        for (int idx = t; idx < 1024; idx += 256) {
            int n = idx & 63, k = 48 + (idx >> 6);
            Ws[n * SX + k] = 0;
        }
    }
    __syncthreads();

    int wave = t >> 6, lane = t & 63;
    int fi = lane & 15, quad = lane >> 4;
    int arow = wave * 16 + fi;

    floatx4 accA[4], accM[4];
#pragma unroll
    for (int i = 0; i < 4; ++i) { accA[i] = (floatx4){0.f,0.f,0.f,0.f}; accM[i] = (floatx4){0.f,0.f,0.f,0.f}; }
#pragma unroll
    for (int ks = 0; ks < KT / 32; ++ks) {
        constexpr bool hasMid = BIN16 && (KDIM == 64);
        short8 af = *(const short8*)&Xs[arow * SX + ks * 32 + quad * 8];
        short8 b0 = *(const short8*)&Ws[(0 * 16 + fi) * SX + ks * 32 + quad * 8];
        short8 b1 = *(const short8*)&Ws[(1 * 16 + fi) * SX + ks * 32 + quad * 8];
        short8 b2 = *(const short8*)&Ws[(2 * 16 + fi) * SX + ks * 32 + quad * 8];
        short8 b3 = *(const short8*)&Ws[(3 * 16 + fi) * SX + ks * 32 + quad * 8];
        if (hasMid && ks >= 2 && ks < 4) {
            accM[0] = __builtin_amdgcn_mfma_f32_16x16x32_bf16(af, b0, accM[0], 0, 0, 0);
            accM[1] = __builtin_amdgcn_mfma_f32_16x16x32_bf16(af, b1, accM[1], 0, 0, 0);
            accM[2] = __builtin_amdgcn_mfma_f32_16x16x32_bf16(af, b2, accM[2], 0, 0, 0);
            accM[3] = __builtin_amdgcn_mfma_f32_16x16x32_bf16(af, b3, accM[3], 0, 0, 0);
        } else {
            accA[0] = __builtin_amdgcn_mfma_f32_16x16x32_bf16(af, b0, accA[0], 0, 0, 0);
            accA[1] = __builtin_amdgcn_mfma_f32_16x16x32_bf16(af, b1, accA[1], 0, 0, 0);
            accA[2] = __builtin_amdgcn_mfma_f32_16x16x32_bf16(af, b2, accA[2], 0, 0, 0);
            accA[3] = __builtin_amdgcn_mfma_f32_16x16x32_bf16(af, b3, accA[3], 0, 0, 0);
        }
    }

    int nbase = blockIdx.x * 64 + wave * 16 + quad * 4;
    float dd[4];
#pragma unroll
    for (int reg = 0; reg < 4; ++reg) {
        if constexpr (BIN16 && KDIM == 64) {
            int node = nbase + reg;
            dd[reg] = dsq[node < N ? node : N - 1];
        } else dd[reg] = 0.f;
    }
    float rv[4][4];
#pragma unroll
    for (int nt = 0; nt < 4; ++nt) {
        int col = nt * 16 + fi;
        float bias = b[col];
#pragma unroll
        for (int reg = 0; reg < 4; ++reg) {
            float v = accA[nt][reg] + bias;
            if constexpr (BIN16 && KDIM == 64) v += accM[nt][reg] * dd[reg];
            rv[nt][reg] = fmaxf(v, 0.f);
        }
    }

    if constexpr (!FUSE_E1) {
#pragma unroll
        for (int nt = 0; nt < 4; ++nt) {
            int col = nt * 16 + fi;
#pragma unroll
            for (int reg = 0; reg < 4; ++reg) {
                int node = nbase + reg;
                if (node < N) outv[(size_t)node * 64 + col] = rv[nt][reg];
            }
        }
    } else {
        __syncthreads();                    // phase-1 LDS dead
        unsigned short* Hs = S;             // 64 x 72
        unsigned short* W2 = S + 64 * 72;   // 128 x 72
        int lrow = wave * 16 + quad * 4;
#pragma unroll
        for (int nt = 0; nt < 4; ++nt) {
#pragma unroll
            for (int reg = 0; reg < 4; ++reg) {
                Hs[(lrow + reg) * 72 + nt * 16 + fi] = bfb(rv[nt][reg]);
            }
        }
        for (int idx = t; idx < 4096; idx += 256) {
            int k = idx >> 6, n = idx & 63;
            float wt = Wt[idx];
            W2[n * 72 + k] = bfb(wt);
            W2[(64 + n) * 72 + k] = bfb(wt + Wp[idx]);
        }
        __syncthreads();

        floatx4 ae[8];
#pragma unroll
        for (int i = 0; i < 8; ++i) ae[i] = (floatx4){0.f,0.f,0.f,0.f};
#pragma unroll
        for (int ks = 0; ks < 2; ++ks) {
            short8 af = *(const short8*)&Hs[arow * 72 + ks * 32 + quad * 8];
#pragma unroll
            for (int nt = 0; nt < 8; ++nt) {
                short8 bf = *(const short8*)&W2[(nt * 16 + fi) * 72 + ks * 32 + quad * 8];
                ae[nt] = __builtin_amdgcn_mfma_f32_16x16x32_bf16(af, bf, ae[nt], 0, 0, 0);
            }
        }
#pragma unroll
        for (int nt = 0; nt < 8; ++nt) {
            int col = nt * 16 + fi;
            if (col < 64) {
#pragma unroll
                for (int reg = 0; reg < 4; ++reg) {
                    int node = nbase + reg;
                    if (node < N) {
                        unsigned u = (unsigned)bfb(ae[nt][reg]) ^ 0x8000u;
                        unsigned key = (u & 0x8000u) ? (~u & 0xffffu) : (u | 0x8000u);
                        md[(size_t)node * 64 + col] = (unsigned short)key;
                    }
                }
            } else {
                int cc = col - 64;
                float bias = bt[cc] + bp[cc];
#pragma unroll
                for (int reg = 0; reg < 4; ++reg) {
                    int node = nbase + reg;
                    if (node < N) pbuf[(size_t)node * 64 + cc] = bfb(ae[nt][reg] + bias);
                }
            }
        }
    }
}

// ---------------- EdgeConv stage 2: padded branch-free packed key-max ----------------
// pbuf is bf16 now.

__global__ __launch_bounds__(256) void k_e2_b(const unsigned short* __restrict__ md,
                                              const unsigned short* __restrict__ pbuf,
                                              const int* __restrict__ row_off, const int* __restrict__ csr,
                                              const float* __restrict__ dinv, unsigned short* __restrict__ out,
                                              unsigned short* __restrict__ outd, int zoff, int N) {
    int node = blockIdx.x * 4 + (threadIdx.x >> 6);
    if (node >= N) return;
    int lane = threadIdx.x & 63;
    int g = lane >> 3;                  // 8 edge groups
    int co = (lane & 7) * 16;           // byte offset of this lane's 8 cols
    int beg = row_off[node], end = row_off[node + 1];
    int deg = end - beg;
    int dmain = deg < 64 ? deg : 64;
    int li = lane < dmain ? lane : dmain - 1;            // clamp (dup last edge)
    int myOff = (deg > 0) ? (csr[beg + li] << 7) : zoff; // deg==0 -> zero page (unused)
    const char* base = (const char*)md + co;
    unsigned k0 = 0, k1 = 0, k2 = 0, k3 = 0;             // 0 <= every real key
    {
        int o0 = __shfl(myOff, g);
        int o1 = __shfl(myOff, 8 + g);
        int o2 = __shfl(myOff, 16 + g);
        int o3 = __shfl(myOff, 24 + g);
        uint4 x0 = *(const uint4*)(base + o0);
        uint4 x1 = *(const uint4*)(base + o1);
        uint4 x2 = *(const uint4*)(base + o2);
        uint4 x3 = *(const uint4*)(base + o3);
        k0 = pkmaxu16(k0, x0.x); k1 = pkmaxu16(k1, x0.y); k2 = pkmaxu16(k2, x0.z); k3 = pkmaxu16(k3, x0.w);
        k0 = pkmaxu16(k0, x1.x); k1 = pkmaxu16(k1, x1.y); k2 = pkmaxu16(k2, x1.z); k3 = pkmaxu16(k3, x1.w);
        k0 = pkmaxu16(k0, x2.x); k1 = pkmaxu16(k1, x2.y); k2 = pkmaxu16(k2, x2.z); k3 = pkmaxu16(k3, x2.w);
        k0 = pkmaxu16(k0, x3.x); k1 = pkmaxu16(k1, x3.y); k2 = pkmaxu16(k2, x3.z); k3 = pkmaxu16(k3, x3.w);
    }
    if (deg > 32) {
        for (int j = 32; j < dmain; j += 8) {            // shfl overshoot -> dup last
            int o = __shfl(myOff, j + g);
            uint4 x = *(const uint4*)(base + o);
            k0 = pkmaxu16(k0, x.x); k1 = pkmaxu16(k1, x.y); k2 = pkmaxu16(k2, x.z); k3 = pkmaxu16(k3, x.w);
        }
        for (int e = beg + 64; e < end; e += 8) {        // deg>64: essentially never
            int idx = e + g;
            int s = csr[idx < end ? idx : end - 1];      // clamp dup (idempotent)
            uint4 x = *(const uint4*)(base + (s << 7));
            k0 = pkmaxu16(k0, x.x); k1 = pkmaxu16(k1, x.y); k2 = pkmaxu16(k2, x.z); k3 = pkmaxu16(k3, x.w);
        }
    }
    k0 = pkmaxu16(k0, __shfl_xor((int)k0, 8)); k0 = pkmaxu16(k0, __shfl_xor((int)k0, 16)); k0 = pkmaxu16(k0, __shfl_xor((int)k0, 32));
    k1 = pkmaxu16(k1, __shfl_xor((int)k1, 8)); k1 = pkmaxu16(k1, __shfl_xor((int)k1, 16)); k1 = pkmaxu16(k1, __shfl_xor((int)k1, 32));
    k2 = pkmaxu16(k2, __shfl_xor((int)k2, 8)); k2 = pkmaxu16(k2, __shfl_xor((int)k2, 16)); k2 = pkmaxu16(k2, __shfl_xor((int)k2, 32));
    k3 = pkmaxu16(k3, __shfl_xor((int)k3, 8)); k3 = pkmaxu16(k3, __shfl_xor((int)k3, 16)); k3 = pkmaxu16(k3, __shfl_xor((int)k3, 32));
    if (g == 0) {                       // lanes 0..7 hold cols lane*8 .. lane*8+7
        unsigned kd[4] = { k0, k1, k2, k3 };
        float a[8];
#pragma unroll
        for (int i = 0; i < 4; ++i) {
            unsigned klo = kd[i] & 0xffffu, khi = kd[i] >> 16;
            unsigned short tlo = (klo & 0x8000u) ? (unsigned short)(klo & 0x7fffu) : (unsigned short)(~klo & 0xffffu);
            unsigned short thi = (khi & 0x8000u) ? (unsigned short)(khi & 0x7fffu) : (unsigned short)(~khi & 0xffffu);
            a[2 * i] = bf2f(tlo);
            a[2 * i + 1] = bf2f(thi);
        }
        float r[8];
        if (end > beg) {
            uint4 pk = *(const uint4*)((const char*)pbuf + (size_t)node * 128 + co);
            unsigned pd4[4] = { pk.x, pk.y, pk.z, pk.w };
#pragma unroll
            for (int i = 0; i < 4; ++i) {
                r[2 * i]     = fmaxf(bf2f((unsigned short)(pd4[i] & 0xffffu)) + a[2 * i], 0.f);
                r[2 * i + 1] = fmaxf(bf2f((unsigned short)(pd4[i] >> 16)) + a[2 * i + 1], 0.f);
            }
        } else {
#pragma unroll
            for (int i = 0; i < 8; ++i) r[i] = 0.f;
        }
        float dn = dinv[node];
        size_t rb = (size_t)node * 128 + co;
        uint4 ub, ud;
        unsigned* pb = (unsigned*)&ub;
        unsigned* pd = (unsigned*)&ud;
#pragma unroll
        for (int i = 0; i < 4; ++i) {
            pb[i] = (unsigned)bfb(r[2 * i]) | ((unsigned)bfb(r[2 * i + 1]) << 16);
            pd[i] = (unsigned)bfb(r[2 * i] * dn) | ((unsigned)bfb(r[2 * i + 1] * dn) << 16);
        }
        *(uint4*)((char*)out + rb) = ub;
        *(uint4*)((char*)outd + rb) = ud;
    }
}

// ---------------- graph mean pooling (segmented: gid is sorted) ----------------

__global__ __launch_bounds__(256) void k_pool(const float* __restrict__ h, const int* __restrict__ gid,
                                              float* __restrict__ out, float* __restrict__ gcnt, int N) {
    const int CHUNK = 128;
    int wave = blockIdx.x * 4 + (threadIdx.x >> 6);
    int lane = threadIdx.x & 63;
    int beg = wave * CHUNK;
    if (beg >= N) return;
    int end = beg + CHUNK < N ? beg + CHUNK : N;
    int gcur = gid[beg];
    float acc = 0.f;
    int cnt = 0;
    for (int n = beg; n < end; ++n) {
        int g = gid[n];
        float v = h[n * 64 + lane];
        if (g != gcur) {
            atomicAdd(&out[gcur * 64 + lane], acc);
            if (lane == 0) atomicAdd(&gcnt[gcur], (float)cnt);
            gcur = g; acc = 0.f; cnt = 0;
        }
        acc += v;
        ++cnt;
    }
    atomicAdd(&out[gcur * 64 + lane], acc);
    if (lane == 0) atomicAdd(&gcnt[gcur], (float)cnt);
}

__global__ __launch_bounds__(256) void k_div(float* __restrict__ out, const float* __restrict__ gcnt, int total) {
    int i = blockIdx.x * blockDim.x + threadIdx.x;
    if (i < total) out[i] /= fmaxf(gcnt[i >> 6], 1.f);
}

// ---------------- launcher ----------------

extern "C" void kernel_launch(void* const* d_in, const int* in_sizes, int n_in,
                              void* d_out, int out_size, void* d_ws, size_t ws_size,
                              hipStream_t stream) {
    const float* feat = (const float*)d_in[0];
    const int* src = (const int*)d_in[1];
    const int* dst = (const int*)d_in[2];
    const int* gid = (const int*)d_in[3];
    const float* W1 = (const float*)d_in[4];  const float* b1 = (const float*)d_in[5];
    const float* W2 = (const float*)d_in[6];  const float* b2 = (const float*)d_in[7];
    const float* W3 = (const float*)d_in[8];  const float* b3 = (const float*)d_in[9];
    const float* Wt1 = (const float*)d_in[10]; const float* bt1 = (const float*)d_in[11];
    const float* Wp1 = (const float*)d_in[12]; const float* bp1 = (const float*)d_in[13];
    const float* Wt2 = (const float*)d_in[14]; const float* bt2 = (const float*)d_in[15];
    const float* Wp2 = (const float*)d_in[16]; const float* bp2 = (const float*)d_in[17];
    float* out = (float*)d_out;

    const int N = in_sizes[0] / 16;
    const int E = in_sizes[1];
    const int G = out_size / 64;
    const int nb = (N + 255) >> 8;      // buckets (<= 512)

    char* p = (char*)d_ws;
    auto alloc = [&](size_t nbytes) {
        void* r = (void*)p;
        p += (nbytes + 255) & ~(size_t)255;
        return r;
    };
    // zero-block first: bcnt | zpage | gcnt contiguous -> single memset
    int* bcnt     = (int*)alloc(512 * 4);
    char* zpage   = (char*)alloc(256);
    float* gcnt   = (float*)alloc((size_t)G * 4);
    size_t zspan  = (size_t)((char*)gcnt - (char*)bcnt) + (((size_t)G * 4 + 255) & ~(size_t)255);
    int* boff     = (int*)alloc(513 * 4);
    int* bcur     = (int*)alloc(512 * 4);
    int* row_off  = (int*)alloc((size_t)(N + 1) * 4);
    int* csr      = (int*)alloc((size_t)E * 4);
    float* dinv   = (float*)alloc((size_t)N * 4);
    float* dsq    = (float*)alloc((size_t)N * 4);
    float* bufA   = (float*)alloc((size_t)N * 64 * 4);
    float* bufB   = (float*)alloc((size_t)N * 64 * 4);
    float* bufC   = (float*)alloc((size_t)N * 64 * 4);
    float* bufD   = (float*)alloc((size_t)N * 64 * 4);
    unsigned short* md   = (unsigned short*)alloc((size_t)N * 64 * 2);
    unsigned short* pbuf = (unsigned short*)alloc((size_t)N * 64 * 2);

    unsigned* ebuf = (unsigned*)bufA;            // alias: bufA dead until after CSR build
    unsigned short* hd = (unsigned short*)bufC;  // dinv-scaled h (gather operand)
    unsigned short* xd = hd + (size_t)N * 64;    // dinv-scaled X1 (layers 1,2)
    unsigned short* xd3 = (unsigned short*)bufA; // dinv-scaled X1 for layer 3 (bufA free by then)
    unsigned short* hD = (unsigned short*)bufD;  // e2 bf16 output (unscaled)
    unsigned short* bufB16 = (unsigned short*)bufB;

    const int zo_hd = (int)((char*)zpage - (char*)hd);
    const int zo_xd = (int)((char*)zpage - (char*)xd);
    const int zo_xd3 = (int)((char*)zpage - (char*)xd3);
    const int zo_md = (int)((char*)zpage - (char*)md);

    hipMemsetAsync(bcnt, 0, zspan, stream);
    hipMemsetAsync(d_out, 0, (size_t)out_size * 4, stream);

    const int nb16 = (N * 16 + 255) / 256;
    const int nbw = (N + 3) / 4;
    const int npool = ((N + 127) / 128 + 3) / 4;
    const int nbt = (N + 63) / 64;
    const int npart = (E + PCHUNK - 1) / PCHUNK;

    // ---- bucketed CSR build (4 launches)
    k_bhist<<<256, 256, 0, stream>>>(dst, bcnt, E);
    k_scanBkt<<<1, 512, 0, stream>>>(bcnt, boff, bcur, nb, E);
    k_partA<<<npart, 256, 0, stream>>>(src, dst, bcur, ebuf, E);
    k_finish<<<nb, 256, 0, stream>>>(ebuf, boff, row_off, dinv, dsq, csr, N, E);

    // ---- Cheb layer 1 (IN=16) + EdgeConv1 stage 1 (fused)
    k_feat16<<<nb16, 256, 0, stream>>>(feat, dinv, hd, N * 16);
    k_aggr16<<<nbw, 256, 0, stream>>>(hd, nullptr, dinv, row_off, csr, bufA, xd, -1.f, 0.f, zo_hd, N);
    k_aggr16<<<nbw, 256, 0, stream>>>(xd, feat, dinv, row_off, csr, bufB, nullptr, -2.f, -1.f, zo_xd, N);
    k_cheb<16, false, true><<<nbt, 256, 0, stream>>>(feat, bufA, bufB, nullptr, W1, b1,
                                                     Wt1, Wp1, bt1, bp1, md, pbuf, nullptr, N);
    k_e2_b<<<nbw, 256, 0, stream>>>(md, pbuf, row_off, csr, dinv, hD, hd, zo_md, N);

    // ---- Cheb layer 2 + EdgeConv2 stage 1 (fused)
    k_aggr64<<<nbw, 256, 0, stream>>>(hd, nullptr, dinv, row_off, csr, nullptr, xd, -1.f, 0.f, zo_hd, N);
    k_aggr64<<<nbw, 256, 0, stream>>>(xd, hD, dinv, row_off, csr, bufB16, nullptr, -2.f, -1.f, zo_xd, N);
    k_cheb<64, true, true><<<nbt, 256, 0, stream>>>(hD, xd, bufB16, dsq, W2, b2,
                                                    Wt2, Wp2, bt2, bp2, md, pbuf, nullptr, N);
    k_e2_b<<<nbw, 256, 0, stream>>>(md, pbuf, row_off, csr, dinv, hD, hd, zo_md, N);

    // ---- Cheb layer 3 (fp32 out -> pooling); xd lives in bufA to avoid bufC overwrite race
    k_aggr64<<<nbw, 256, 0, stream>>>(hd, nullptr, dinv, row_off, csr, nullptr, xd3, -1.f, 0.f, zo_hd, N);
    k_aggr64<<<nbw, 256, 0, stream>>>(xd3, hD, dinv, row_off, csr, bufB16, nullptr, -2.f, -1.f, zo_xd3, N);
    k_cheb<64, true, false><<<nbt, 256, 0, stream>>>(hD, xd3, bufB16, dsq, W3, b3,
                                                     nullptr, nullptr, nullptr, nullptr,
                                                     nullptr, nullptr, bufC, N);

    // ---- per-graph mean pooling
    k_pool<<<npool, 256, 0, stream>>>(bufC, gid, out, gcnt, N);
    k_div<<<(out_size + 255) / 256, 256, 0, stream>>>(out, gcnt, out_size);
}

// Round 6
// 533.671 us; speedup vs baseline: 1.1642x; 1.0650x over previous
//
#include <hip/hip_runtime.h>
#include <hip/hip_bf16.h>
#include <math.h>

typedef __attribute__((ext_vector_type(8))) short short8;
typedef __attribute__((ext_vector_type(4))) float floatx4;

__device__ __forceinline__ unsigned short bfb(float x) {
    union { __hip_bfloat16 h; unsigned short u; } c;
    c.h = __float2bfloat16(x);
    return c.u;
}
__device__ __forceinline__ float bf2f(unsigned short u) {
    union { unsigned int i; float f; } c;
    c.i = ((unsigned int)u) << 16;
    return c.f;
}
// accumulate the two bf16 halves of a dword into two f32 accumulators
__device__ __forceinline__ void acc2(float& lo, float& hi, unsigned d) {
    union { unsigned u; float f; } a, b;
    a.u = d << 16;
    b.u = d & 0xffff0000u;
    lo += a.f; hi += b.f;
}
// packed unsigned 16-bit max (gfx9 VOP3P, inherited on CDNA4)
__device__ __forceinline__ unsigned pkmaxu16(unsigned a, unsigned b) {
    unsigned d;
    asm("v_pk_max_u16 %0, %1, %2" : "=v"(d) : "v"(a), "v"(b));
    return d;
}

// ---------------- bucketed CSR build v3 ----------------

__global__ __launch_bounds__(256) void k_bhist(const int* __restrict__ dst, int* __restrict__ bcnt, int E) {
    __shared__ int h[512];
    int t = threadIdx.x;
    for (int i = t; i < 512; i += 256) h[i] = 0;
    __syncthreads();
    int step = gridDim.x * 256;
    for (int i = blockIdx.x * 256 + t; i < E; i += step) atomicAdd(&h[dst[i] >> 8], 1);
    __syncthreads();
    for (int i = t; i < 512; i += 256) if (h[i]) atomicAdd(&bcnt[i], h[i]);
}

__global__ __launch_bounds__(512) void k_scanBkt(const int* __restrict__ bcnt, int* __restrict__ boff,
                                                 int* __restrict__ bcur, int nb, int E) {
    __shared__ int s[512];
    int t = threadIdx.x;
    int v = (t < nb) ? bcnt[t] : 0;
    s[t] = v;
    __syncthreads();
    for (int off = 1; off < 512; off <<= 1) {
        int x = (t >= off) ? s[t - off] : 0;
        __syncthreads();
        s[t] += x;
        __syncthreads();
    }
    if (t < nb) { boff[t] = s[t] - v; bcur[t] = s[t] - v; }
    if (t == 0) boff[nb] = E;
}

#define PCHUNK 8192

__global__ __launch_bounds__(256) void k_partA(const int* __restrict__ src, const int* __restrict__ dst,
                                               int* __restrict__ bcur, unsigned* __restrict__ ebuf, int E) {
    __shared__ int h[512];
    __shared__ int base[512];
    int t = threadIdx.x;
    for (int i = t; i < 512; i += 256) h[i] = 0;
    __syncthreads();
    int start = blockIdx.x * PCHUNK;
    int end = start + PCHUNK < E ? start + PCHUNK : E;
    for (int i = start + t; i < end; i += 256) atomicAdd(&h[dst[i] >> 8], 1);
    __syncthreads();
    for (int i = t; i < 512; i += 256) {
        int c = h[i];
        base[i] = c ? atomicAdd(&bcur[i], c) : 0;
        h[i] = 0;
    }
    __syncthreads();
    for (int i = start + t; i < end; i += 256) {
        int d = dst[i];
        int b = d >> 8;
        int r = atomicAdd(&h[b], 1);
        ebuf[base[b] + r] = ((unsigned)src[i] << 8) | (unsigned)(d & 255);
    }
}

// k_finish + fused feat16: also emits bf16 dinv-scaled features (hd)
__global__ __launch_bounds__(256) void k_finish(const unsigned* __restrict__ ebuf, const int* __restrict__ boff,
                                                int* __restrict__ row_off, float* __restrict__ dinv,
                                                float* __restrict__ dsq, int* __restrict__ csr,
                                                const float* __restrict__ feat, unsigned short* __restrict__ hd,
                                                int N, int E) {
    __shared__ int h[256];
    __shared__ int sc[256];
    __shared__ int cur[256];
    int b = blockIdx.x, t = threadIdx.x;
    h[t] = 0;
    __syncthreads();
    int beg = boff[b], end = boff[b + 1];
    for (int e = beg + t; e < end; e += 256) atomicAdd(&h[ebuf[e] & 255], 1);
    __syncthreads();
    int v = h[t];
    sc[t] = v;
    __syncthreads();
    for (int off = 1; off < 256; off <<= 1) {
        int x = (t >= off) ? sc[t - off] : 0;
        __syncthreads();
        sc[t] += x;
        __syncthreads();
    }
    int node = (b << 8) + t;
    int excl = beg + sc[t] - v;
    if (node < N) {
        row_off[node] = excl;
        float dg = (float)(v > 1 ? v : 1);
        float dv = rsqrtf(dg);
        dinv[node] = dv;
        dsq[node] = sqrtf(dg);
        const float* f = &feat[(size_t)node * 16];
#pragma unroll
        for (int k = 0; k < 16; k += 4) {
            float4 x = *(const float4*)&f[k];
            ushort4 u = { bfb(x.x * dv), bfb(x.y * dv), bfb(x.z * dv), bfb(x.w * dv) };
            *(ushort4*)&hd[(size_t)node * 16 + k] = u;
        }
    }
    cur[t] = excl;
    if (b == 0 && t == 0) row_off[N] = E;
    __syncthreads();
    for (int e = beg + t; e < end; e += 256) {
        unsigned ed = ebuf[e];
        int pos = atomicAdd(&cur[ed & 255], 1);
        csr[pos] = (int)(ed >> 8);
    }
}

// ---------------- 16-dim Chebyshev aggregation, padded branch-free (bf16 out) ----------------

__global__ __launch_bounds__(256) void k_aggr16(const unsigned short* __restrict__ Xd, const float* __restrict__ Z,
                                                const float* __restrict__ dinv,
                                                const int* __restrict__ row_off, const int* __restrict__ csr,
                                                unsigned short* __restrict__ outb, unsigned short* __restrict__ outd,
                                                float alpha, float beta, int zoff, int N) {
    int node = blockIdx.x * 4 + (threadIdx.x >> 6);
    if (node >= N) return;
    int lane = threadIdx.x & 63;
    int g = lane >> 2;                  // 16 edge groups
    int co = (lane & 3) * 8;            // byte offset of this lane's 4 cols
    int beg = row_off[node], end = row_off[node + 1];
    int deg = end - beg;
    int myOff = (lane < deg) ? (csr[beg + lane] << 5) : zoff;   // 32B rows; pad -> zero page
    const char* base = (const char*)Xd + co;
    float a0 = 0.f, a1 = 0.f, a2 = 0.f, a3 = 0.f;
    {
        int o0 = __shfl(myOff, g);
        int o1 = __shfl(myOff, 16 + g);
        ushort4 x0 = *(const ushort4*)(base + o0);
        ushort4 x1 = *(const ushort4*)(base + o1);
        a0 += bf2f(x0.x); a1 += bf2f(x0.y); a2 += bf2f(x0.z); a3 += bf2f(x0.w);
        a0 += bf2f(x1.x); a1 += bf2f(x1.y); a2 += bf2f(x1.z); a3 += bf2f(x1.w);
    }
    if (deg > 32) {
        int dmain = deg < 64 ? deg : 64;
        for (int j = 32; j < dmain; j += 16) {           // shfl overshoot -> zero page
            int o = __shfl(myOff, j + g);
            ushort4 x = *(const ushort4*)(base + o);
            a0 += bf2f(x.x); a1 += bf2f(x.y); a2 += bf2f(x.z); a3 += bf2f(x.w);
        }
        for (int e = beg + 64; e < end; e += 16) {       // deg>64: essentially never
            int idx = e + g;
            int s = csr[idx < end ? idx : end - 1];
            ushort4 x = *(const ushort4*)(base + (s << 5));
            if (idx < end) {
                a0 += bf2f(x.x); a1 += bf2f(x.y); a2 += bf2f(x.z); a3 += bf2f(x.w);
            }
        }
    }
    a0 += __shfl_xor(a0, 4); a0 += __shfl_xor(a0, 8); a0 += __shfl_xor(a0, 16); a0 += __shfl_xor(a0, 32);
    a1 += __shfl_xor(a1, 4); a1 += __shfl_xor(a1, 8); a1 += __shfl_xor(a1, 16); a1 += __shfl_xor(a1, 32);
    a2 += __shfl_xor(a2, 4); a2 += __shfl_xor(a2, 8); a2 += __shfl_xor(a2, 16); a2 += __shfl_xor(a2, 32);
    a3 += __shfl_xor(a3, 4); a3 += __shfl_xor(a3, 8); a3 += __shfl_xor(a3, 16); a3 += __shfl_xor(a3, 32);
    if (g == 0) {
        int c4 = (lane & 3) * 4;
        float dn = dinv[node];
        float v0 = alpha * dn * a0;
        float v1 = alpha * dn * a1;
        float v2 = alpha * dn * a2;
        float v3 = alpha * dn * a3;
        if (Z) {
            float4 zv = *(const float4*)&Z[(size_t)node * 16 + c4];
            v0 += beta * zv.x; v1 += beta * zv.y; v2 += beta * zv.z; v3 += beta * zv.w;
        }
        ushort4 ub = { bfb(v0), bfb(v1), bfb(v2), bfb(v3) };
        *(ushort4*)&outb[(size_t)node * 16 + c4] = ub;
        if (outd) {
            ushort4 u = { bfb(v0 * dn), bfb(v1 * dn), bfb(v2 * dn), bfb(v3 * dn) };
            *(ushort4*)&outd[(size_t)node * 16 + c4] = u;
        }
    }
}

// ---------------- 64-dim Chebyshev aggregation, padded branch-free ----------------
// outb optional (X1 pass writes only the dinv-scaled copy; cheb rescales via dsq).

__global__ __launch_bounds__(256) void k_aggr64(const unsigned short* __restrict__ Xd,
                                                const unsigned short* __restrict__ Z,
                                                const float* __restrict__ dinv,
                                                const int* __restrict__ row_off, const int* __restrict__ csr,
                                                unsigned short* __restrict__ outb, unsigned short* __restrict__ outd,
                                                float alpha, float beta, int zoff, int N) {
    int node = blockIdx.x * 4 + (threadIdx.x >> 6);
    if (node >= N) return;
    int lane = threadIdx.x & 63;
    int g = lane >> 3;                  // 8 edge groups
    int co = (lane & 7) * 16;           // byte offset of this lane's 8 cols
    int beg = row_off[node], end = row_off[node + 1];
    int deg = end - beg;
    int myOff = (lane < deg) ? (csr[beg + lane] << 7) : zoff;   // 128B rows; pad -> zero page
    const char* base = (const char*)Xd + co;
    float a0 = 0.f, a1 = 0.f, a2 = 0.f, a3 = 0.f, a4 = 0.f, a5 = 0.f, a6 = 0.f, a7 = 0.f;
    {
        int o0 = __shfl(myOff, g);
        int o1 = __shfl(myOff, 8 + g);
        int o2 = __shfl(myOff, 16 + g);
        int o3 = __shfl(myOff, 24 + g);
        uint4 x0 = *(const uint4*)(base + o0);
        uint4 x1 = *(const uint4*)(base + o1);
        uint4 x2 = *(const uint4*)(base + o2);
        uint4 x3 = *(const uint4*)(base + o3);
        acc2(a0, a1, x0.x); acc2(a2, a3, x0.y); acc2(a4, a5, x0.z); acc2(a6, a7, x0.w);
        acc2(a0, a1, x1.x); acc2(a2, a3, x1.y); acc2(a4, a5, x1.z); acc2(a6, a7, x1.w);
        acc2(a0, a1, x2.x); acc2(a2, a3, x2.y); acc2(a4, a5, x2.z); acc2(a6, a7, x2.w);
        acc2(a0, a1, x3.x); acc2(a2, a3, x3.y); acc2(a4, a5, x3.z); acc2(a6, a7, x3.w);
    }
    if (deg > 32) {
        int dmain = deg < 64 ? deg : 64;
        for (int j = 32; j < dmain; j += 8) {            // shfl overshoot -> zero page
            int o = __shfl(myOff, j + g);
            uint4 x = *(const uint4*)(base + o);
            acc2(a0, a1, x.x); acc2(a2, a3, x.y); acc2(a4, a5, x.z); acc2(a6, a7, x.w);
        }
        for (int e = beg + 64; e < end; e += 8) {        // deg>64: essentially never
            int idx = e + g;
            int s = csr[idx < end ? idx : end - 1];
            uint4 x = *(const uint4*)(base + (s << 7));
            if (idx < end) {
                acc2(a0, a1, x.x); acc2(a2, a3, x.y); acc2(a4, a5, x.z); acc2(a6, a7, x.w);
            }
        }
    }
    a0 += __shfl_xor(a0, 8); a0 += __shfl_xor(a0, 16); a0 += __shfl_xor(a0, 32);
    a1 += __shfl_xor(a1, 8); a1 += __shfl_xor(a1, 16); a1 += __shfl_xor(a1, 32);
    a2 += __shfl_xor(a2, 8); a2 += __shfl_xor(a2, 16); a2 += __shfl_xor(a2, 32);
    a3 += __shfl_xor(a3, 8); a3 += __shfl_xor(a3, 16); a3 += __shfl_xor(a3, 32);
    a4 += __shfl_xor(a4, 8); a4 += __shfl_xor(a4, 16); a4 += __shfl_xor(a4, 32);
    a5 += __shfl_xor(a5, 8); a5 += __shfl_xor(a5, 16); a5 += __shfl_xor(a5, 32);
    a6 += __shfl_xor(a6, 8); a6 += __shfl_xor(a6, 16); a6 += __shfl_xor(a6, 32);
    a7 += __shfl_xor(a7, 8); a7 += __shfl_xor(a7, 16); a7 += __shfl_xor(a7, 32);
    if (g == 0) {                       // lanes 0..7 hold cols lane*8 .. lane*8+7
        float dn = dinv[node];
        float v[8] = { a0, a1, a2, a3, a4, a5, a6, a7 };
#pragma unroll
        for (int i = 0; i < 8; ++i) v[i] *= alpha * dn;
        size_t rb = (size_t)node * 128 + co;            // byte offset of this lane's span
        if (Z) {
            uint4 zv = *(const uint4*)((const char*)Z + rb);
            unsigned zd[4] = { zv.x, zv.y, zv.z, zv.w };
#pragma unroll
            for (int i = 0; i < 4; ++i) {
                union { unsigned u; float f; } lo, hi;
                lo.u = zd[i] << 16; hi.u = zd[i] & 0xffff0000u;
                v[2 * i] += beta * lo.f;
                v[2 * i + 1] += beta * hi.f;
            }
        }
        if (outb) {
            uint4 ub;
            unsigned* pb = (unsigned*)&ub;
#pragma unroll
            for (int i = 0; i < 4; ++i)
                pb[i] = (unsigned)bfb(v[2 * i]) | ((unsigned)bfb(v[2 * i + 1]) << 16);
            *(uint4*)((char*)outb + rb) = ub;
        }
        if (outd) {
            uint4 ud;
            unsigned* pd = (unsigned*)&ud;
#pragma unroll
            for (int i = 0; i < 4; ++i)
                pd[i] = (unsigned)bfb(v[2 * i] * dn) | ((unsigned)bfb(v[2 * i + 1] * dn) << 16);
            *(uint4*)((char*)outd + rb) = ud;
        }
    }
}

// ---------------- fused Cheb matmul (+ EdgeConv stage 1 | atomic mean-pool) ----------------
// KDIM=16: X0 = f32 feat, X1/X2 = bf16. KDIM=64: all bf16; X1 = dinv-scaled xd ->
// mid-K-segment accumulated separately and row-scaled by dsq (commutes with K-sum).
// FUSE_E1: cheb ReLU -> LDS -> e1 MFMA [m|p]; emits md keys + bf16 pbuf.
// POOLOUT: epilogue accumulates per-graph mean-pool (sorted gid -> wave-reduced atomics).

template <int KDIM, bool FUSE_E1, bool POOLOUT>
__global__ __launch_bounds__(256) void k_cheb(const void* __restrict__ X0v, const void* __restrict__ X1v,
                                              const void* __restrict__ X2v, const float* __restrict__ dsq,
                                              const float* __restrict__ W, const float* __restrict__ bvec,
                                              const float* __restrict__ Wt, const float* __restrict__ Wp,
                                              const float* __restrict__ bt, const float* __restrict__ bp,
                                              unsigned short* __restrict__ md, unsigned short* __restrict__ pbuf,
                                              const int* __restrict__ gid, float* __restrict__ out, int N) {
    constexpr int KT = (KDIM == 16) ? 64 : 3 * KDIM;
    constexpr int SX = KT + 8;
    constexpr int PH1 = 2 * 64 * SX;
    constexpr int PH2 = FUSE_E1 ? (64 * 72 + 128 * 72) : 0;
    constexpr int SSZ = PH1 > PH2 ? PH1 : PH2;
    constexpr bool hasMid = (KDIM == 64);
    __shared__ unsigned short S[SSZ];
    unsigned short* Xs = S;
    unsigned short* Ws = S + 64 * SX;
    int t = threadIdx.x;

    {
        int sn = t & 63;
        int gn = blockIdx.x * 64 + sn; if (gn >= N) gn = N - 1;
        int k0 = (t >> 6) * (KDIM / 4);
        if constexpr (KDIM == 16) {
            // X0 f32 feat
            float4 v = *(const float4*)&((const float*)X0v)[(size_t)gn * 16 + k0];
            ushort4 u = { bfb(v.x), bfb(v.y), bfb(v.z), bfb(v.w) };
            *(ushort4*)&Xs[sn * SX + k0] = u;
            // X1, X2 bf16
            *(ushort4*)&Xs[sn * SX + 16 + k0] =
                *(const ushort4*)&((const unsigned short*)X1v)[(size_t)gn * 16 + k0];
            *(ushort4*)&Xs[sn * SX + 32 + k0] =
                *(const ushort4*)&((const unsigned short*)X2v)[(size_t)gn * 16 + k0];
            int kp = 48 + (t >> 6) * 4;
            ushort4 z = { 0, 0, 0, 0 };
            *(ushort4*)&Xs[sn * SX + kp] = z;
        } else {
            const unsigned short* Xp[3] = { (const unsigned short*)X0v, (const unsigned short*)X1v,
                                            (const unsigned short*)X2v };
#pragma unroll
            for (int a = 0; a < 3; ++a) {
#pragma unroll
                for (int i = 0; i < KDIM / 16; ++i) {
                    *(ushort4*)&Xs[sn * SX + a * KDIM + k0 + 4 * i] =
                        *(const ushort4*)&Xp[a][(size_t)gn * KDIM + k0 + 4 * i];
                }
            }
        }
    }
    for (int idx = t; idx < 3 * KDIM * 64; idx += 256) {
        int a = idx / (KDIM * 64);
        int r = idx % (KDIM * 64);
        int k = r >> 6, n = r & 63;
        Ws[n * SX + a * KDIM + k] = bfb(W[idx]);
    }
    if constexpr (KDIM == 16) {
        for (int idx = t; idx < 1024; idx += 256) {
            int n = idx & 63, k = 48 + (idx >> 6);
            Ws[n * SX + k] = 0;
        }
    }
    __syncthreads();

    int wave = t >> 6, lane = t & 63;
    int fi = lane & 15, quad = lane >> 4;
    int arow = wave * 16 + fi;

    floatx4 accA[4], accM[4];
#pragma unroll
    for (int i = 0; i < 4; ++i) { accA[i] = (floatx4){0.f,0.f,0.f,0.f}; accM[i] = (floatx4){0.f,0.f,0.f,0.f}; }
#pragma unroll
    for (int ks = 0; ks < KT / 32; ++ks) {
        short8 af = *(const short8*)&Xs[arow * SX + ks * 32 + quad * 8];
        short8 b0 = *(const short8*)&Ws[(0 * 16 + fi) * SX + ks * 32 + quad * 8];
        short8 b1 = *(const short8*)&Ws[(1 * 16 + fi) * SX + ks * 32 + quad * 8];
        short8 b2 = *(const short8*)&Ws[(2 * 16 + fi) * SX + ks * 32 + quad * 8];
        short8 b3 = *(const short8*)&Ws[(3 * 16 + fi) * SX + ks * 32 + quad * 8];
        if (hasMid && ks >= 2 && ks < 4) {
            accM[0] = __builtin_amdgcn_mfma_f32_16x16x32_bf16(af, b0, accM[0], 0, 0, 0);
            accM[1] = __builtin_amdgcn_mfma_f32_16x16x32_bf16(af, b1, accM[1], 0, 0, 0);
            accM[2] = __builtin_amdgcn_mfma_f32_16x16x32_bf16(af, b2, accM[2], 0, 0, 0);
            accM[3] = __builtin_amdgcn_mfma_f32_16x16x32_bf16(af, b3, accM[3], 0, 0, 0);
        } else {
            accA[0] = __builtin_amdgcn_mfma_f32_16x16x32_bf16(af, b0, accA[0], 0, 0, 0);
            accA[1] = __builtin_amdgcn_mfma_f32_16x16x32_bf16(af, b1, accA[1], 0, 0, 0);
            accA[2] = __builtin_amdgcn_mfma_f32_16x16x32_bf16(af, b2, accA[2], 0, 0, 0);
            accA[3] = __builtin_amdgcn_mfma_f32_16x16x32_bf16(af, b3, accA[3], 0, 0, 0);
        }
    }

    int nbase0 = blockIdx.x * 64 + wave * 16;
    int nbase = nbase0 + quad * 4;
    float dd[4];
#pragma unroll
    for (int reg = 0; reg < 4; ++reg) {
        if constexpr (hasMid) {
            int node = nbase + reg;
            dd[reg] = dsq[node < N ? node : N - 1];
        } else dd[reg] = 0.f;
    }
    float rv[4][4];
#pragma unroll
    for (int nt = 0; nt < 4; ++nt) {
        int col = nt * 16 + fi;
        float bias = bvec[col];
#pragma unroll
        for (int reg = 0; reg < 4; ++reg) {
            float v = accA[nt][reg] + bias;
            if constexpr (hasMid) v += accM[nt][reg] * dd[reg];
            rv[nt][reg] = fmaxf(v, 0.f);
        }
    }

    if constexpr (POOLOUT) {
        int gfirst = gid[nbase0 < N ? nbase0 : N - 1];
        int lastn = nbase0 + 15;
        int glast = gid[lastn < N ? lastn : N - 1];
        bool uniform = (lastn < N) && (gfirst == glast);     // wave-uniform branch
        if (uniform) {
#pragma unroll
            for (int nt = 0; nt < 4; ++nt) {
                float s = (rv[nt][0] + rv[nt][1]) + (rv[nt][2] + rv[nt][3]);
                s += __shfl_xor(s, 16); s += __shfl_xor(s, 32);
                if (quad == 0) atomicAdd(&out[(size_t)gfirst * 64 + nt * 16 + fi], s);
            }
        } else {
#pragma unroll
            for (int reg = 0; reg < 4; ++reg) {
                int node = nbase + reg;
                if (node < N) {
                    int g = gid[node];
#pragma unroll
                    for (int nt = 0; nt < 4; ++nt)
                        atomicAdd(&out[(size_t)g * 64 + nt * 16 + fi], rv[nt][reg]);
                }
            }
        }
    } else if constexpr (FUSE_E1) {
        __syncthreads();                    // phase-1 LDS dead
        unsigned short* Hs = S;             // 64 x 72
        unsigned short* W2l = S + 64 * 72;  // 128 x 72
        int lrow = wave * 16 + quad * 4;
#pragma unroll
        for (int nt = 0; nt < 4; ++nt)
#pragma unroll
            for (int reg = 0; reg < 4; ++reg)
                Hs[(lrow + reg) * 72 + nt * 16 + fi] = bfb(rv[nt][reg]);
        for (int idx = t; idx < 4096; idx += 256) {
            int k = idx >> 6, n = idx & 63;
            float wt = Wt[idx];
            W2l[n * 72 + k] = bfb(wt);
            W2l[(64 + n) * 72 + k] = bfb(wt + Wp[idx]);
        }
        __syncthreads();
        floatx4 ae[8];
#pragma unroll
        for (int i = 0; i < 8; ++i) ae[i] = (floatx4){0.f,0.f,0.f,0.f};
#pragma unroll
        for (int ks = 0; ks < 2; ++ks) {
            short8 af = *(const short8*)&Hs[arow * 72 + ks * 32 + quad * 8];
#pragma unroll
            for (int nt = 0; nt < 8; ++nt) {
                short8 bf = *(const short8*)&W2l[(nt * 16 + fi) * 72 + ks * 32 + quad * 8];
                ae[nt] = __builtin_amdgcn_mfma_f32_16x16x32_bf16(af, bf, ae[nt], 0, 0, 0);
            }
        }
#pragma unroll
        for (int nt = 0; nt < 8; ++nt) {
            int col = nt * 16 + fi;
            if (col < 64) {
#pragma unroll
                for (int reg = 0; reg < 4; ++reg) {
                    int node = nbase + reg;
                    if (node < N) {
                        unsigned u = (unsigned)bfb(ae[nt][reg]) ^ 0x8000u;
                        unsigned key = (u & 0x8000u) ? (~u & 0xffffu) : (u | 0x8000u);
                        md[(size_t)node * 64 + col] = (unsigned short)key;
                    }
                }
            } else {
                int cc = col - 64;
                float bias2 = bt[cc] + bp[cc];
#pragma unroll
                for (int reg = 0; reg < 4; ++reg) {
                    int node = nbase + reg;
                    if (node < N) pbuf[(size_t)node * 64 + cc] = bfb(ae[nt][reg] + bias2);
                }
            }
        }
    }
}

// ---------------- EdgeConv stage 2: padded branch-free packed key-max ----------------

__global__ __launch_bounds__(256) void k_e2_b(const unsigned short* __restrict__ md,
                                              const unsigned short* __restrict__ pbuf,
                                              const int* __restrict__ row_off, const int* __restrict__ csr,
                                              const float* __restrict__ dinv, unsigned short* __restrict__ out,
                                              unsigned short* __restrict__ outd, int zoff, int N) {
    int node = blockIdx.x * 4 + (threadIdx.x >> 6);
    if (node >= N) return;
    int lane = threadIdx.x & 63;
    int g = lane >> 3;                  // 8 edge groups
    int co = (lane & 7) * 16;           // byte offset of this lane's 8 cols
    int beg = row_off[node], end = row_off[node + 1];
    int deg = end - beg;
    int dmain = deg < 64 ? deg : 64;
    int li = lane < dmain ? lane : dmain - 1;            // clamp (dup last edge)
    int myOff = (deg > 0) ? (csr[beg + li] << 7) : zoff; // deg==0 -> zero page (unused)
    const char* base = (const char*)md + co;
    unsigned k0 = 0, k1 = 0, k2 = 0, k3 = 0;             // 0 <= every real key
    {
        int o0 = __shfl(myOff, g);
        int o1 = __shfl(myOff, 8 + g);
        int o2 = __shfl(myOff, 16 + g);
        int o3 = __shfl(myOff, 24 + g);
        uint4 x0 = *(const uint4*)(base + o0);
        uint4 x1 = *(const uint4*)(base + o1);
        uint4 x2 = *(const uint4*)(base + o2);
        uint4 x3 = *(const uint4*)(base + o3);
        k0 = pkmaxu16(k0, x0.x); k1 = pkmaxu16(k1, x0.y); k2 = pkmaxu16(k2, x0.z); k3 = pkmaxu16(k3, x0.w);
        k0 = pkmaxu16(k0, x1.x); k1 = pkmaxu16(k1, x1.y); k2 = pkmaxu16(k2, x1.z); k3 = pkmaxu16(k3, x1.w);
        k0 = pkmaxu16(k0, x2.x); k1 = pkmaxu16(k1, x2.y); k2 = pkmaxu16(k2, x2.z); k3 = pkmaxu16(k3, x2.w);
        k0 = pkmaxu16(k0, x3.x); k1 = pkmaxu16(k1, x3.y); k2 = pkmaxu16(k2, x3.z); k3 = pkmaxu16(k3, x3.w);
    }
    if (deg > 32) {
        for (int j = 32; j < dmain; j += 8) {            // shfl overshoot -> dup last
            int o = __shfl(myOff, j + g);
            uint4 x = *(const uint4*)(base + o);
            k0 = pkmaxu16(k0, x.x); k1 = pkmaxu16(k1, x.y); k2 = pkmaxu16(k2, x.z); k3 = pkmaxu16(k3, x.w);
        }
        for (int e = beg + 64; e < end; e += 8) {        // deg>64: essentially never
            int idx = e + g;
            int s = csr[idx < end ? idx : end - 1];      // clamp dup (idempotent)
            uint4 x = *(const uint4*)(base + (s << 7));
            k0 = pkmaxu16(k0, x.x); k1 = pkmaxu16(k1, x.y); k2 = pkmaxu16(k2, x.z); k3 = pkmaxu16(k3, x.w);
        }
    }
    k0 = pkmaxu16(k0, __shfl_xor((int)k0, 8)); k0 = pkmaxu16(k0, __shfl_xor((int)k0, 16)); k0 = pkmaxu16(k0, __shfl_xor((int)k0, 32));
    k1 = pkmaxu16(k1, __shfl_xor((int)k1, 8)); k1 = pkmaxu16(k1, __shfl_xor((int)k1, 16)); k1 = pkmaxu16(k1, __shfl_xor((int)k1, 32));
    k2 = pkmaxu16(k2, __shfl_xor((int)k2, 8)); k2 = pkmaxu16(k2, __shfl_xor((int)k2, 16)); k2 = pkmaxu16(k2, __shfl_xor((int)k2, 32));
    k3 = pkmaxu16(k3, __shfl_xor((int)k3, 8)); k3 = pkmaxu16(k3, __shfl_xor((int)k3, 16)); k3 = pkmaxu16(k3, __shfl_xor((int)k3, 32));
    if (g == 0) {                       // lanes 0..7 hold cols lane*8 .. lane*8+7
        unsigned kd[4] = { k0, k1, k2, k3 };
        float a[8];
#pragma unroll
        for (int i = 0; i < 4; ++i) {
            unsigned klo = kd[i] & 0xffffu, khi = kd[i] >> 16;
            unsigned short tlo = (klo & 0x8000u) ? (unsigned short)(klo & 0x7fffu) : (unsigned short)(~klo & 0xffffu);
            unsigned short thi = (khi & 0x8000u) ? (unsigned short)(khi & 0x7fffu) : (unsigned short)(~khi & 0xffffu);
            a[2 * i] = bf2f(tlo);
            a[2 * i + 1] = bf2f(thi);
        }
        float r[8];
        if (end > beg) {
            uint4 pk = *(const uint4*)((const char*)pbuf + (size_t)node * 128 + co);
            unsigned pd4[4] = { pk.x, pk.y, pk.z, pk.w };
#pragma unroll
            for (int i = 0; i < 4; ++i) {
                r[2 * i]     = fmaxf(bf2f((unsigned short)(pd4[i] & 0xffffu)) + a[2 * i], 0.f);
                r[2 * i + 1] = fmaxf(bf2f((unsigned short)(pd4[i] >> 16)) + a[2 * i + 1], 0.f);
            }
        } else {
#pragma unroll
            for (int i = 0; i < 8; ++i) r[i] = 0.f;
        }
        float dn = dinv[node];
        size_t rb = (size_t)node * 128 + co;
        uint4 ub, ud;
        unsigned* pb = (unsigned*)&ub;
        unsigned* pd = (unsigned*)&ud;
#pragma unroll
        for (int i = 0; i < 4; ++i) {
            pb[i] = (unsigned)bfb(r[2 * i]) | ((unsigned)bfb(r[2 * i + 1]) << 16);
            pd[i] = (unsigned)bfb(r[2 * i] * dn) | ((unsigned)bfb(r[2 * i + 1] * dn) << 16);
        }
        *(uint4*)((char*)out + rb) = ub;
        *(uint4*)((char*)outd + rb) = ud;
    }
}

// ---------------- final divide: per-graph count via binary search on sorted gid ----------------

__global__ __launch_bounds__(256) void k_div(float* __restrict__ out, const int* __restrict__ gid,
                                             int N, int total) {
    int i = blockIdx.x * blockDim.x + threadIdx.x;
    if (i >= total) return;
    int g = i >> 6;
    int lo = 0, hi = N;
    while (lo < hi) { int m = (lo + hi) >> 1; if (gid[m] < g) lo = m + 1; else hi = m; }
    int s = lo;
    hi = N;
    while (lo < hi) { int m = (lo + hi) >> 1; if (gid[m] < g + 1) lo = m + 1; else hi = m; }
    float c = (float)(lo - s);
    out[i] /= fmaxf(c, 1.f);
}

// ---------------- launcher ----------------

extern "C" void kernel_launch(void* const* d_in, const int* in_sizes, int n_in,
                              void* d_out, int out_size, void* d_ws, size_t ws_size,
                              hipStream_t stream) {
    const float* feat = (const float*)d_in[0];
    const int* src = (const int*)d_in[1];
    const int* dst = (const int*)d_in[2];
    const int* gid = (const int*)d_in[3];
    const float* W1 = (const float*)d_in[4];  const float* b1 = (const float*)d_in[5];
    const float* W2 = (const float*)d_in[6];  const float* b2 = (const float*)d_in[7];
    const float* W3 = (const float*)d_in[8];  const float* b3 = (const float*)d_in[9];
    const float* Wt1 = (const float*)d_in[10]; const float* bt1 = (const float*)d_in[11];
    const float* Wp1 = (const float*)d_in[12]; const float* bp1 = (const float*)d_in[13];
    const float* Wt2 = (const float*)d_in[14]; const float* bt2 = (const float*)d_in[15];
    const float* Wp2 = (const float*)d_in[16]; const float* bp2 = (const float*)d_in[17];
    float* out = (float*)d_out;

    const int N = in_sizes[0] / 16;
    const int E = in_sizes[1];
    const int nb = (N + 255) >> 8;      // buckets (<= 512)

    char* p = (char*)d_ws;
    auto alloc = [&](size_t nbytes) {
        void* r = (void*)p;
        p += (nbytes + 255) & ~(size_t)255;
        return r;
    };
    // zero-block first: bcnt | zpage contiguous -> single memset
    int* bcnt     = (int*)alloc(512 * 4);
    char* zpage   = (char*)alloc(256);
    size_t zspan  = (size_t)((char*)zpage - (char*)bcnt) + 256;
    int* boff     = (int*)alloc(513 * 4);
    int* bcur     = (int*)alloc(512 * 4);
    int* row_off  = (int*)alloc((size_t)(N + 1) * 4);
    int* csr      = (int*)alloc((size_t)E * 4);
    float* dinv   = (float*)alloc((size_t)N * 4);
    float* dsq    = (float*)alloc((size_t)N * 4);
    float* bufA   = (float*)alloc((size_t)N * 64 * 4);
    float* bufB   = (float*)alloc((size_t)N * 64 * 4);
    float* bufC   = (float*)alloc((size_t)N * 64 * 4);
    float* bufD   = (float*)alloc((size_t)N * 64 * 4);
    unsigned short* md   = (unsigned short*)alloc((size_t)N * 64 * 2);
    unsigned short* pbuf = (unsigned short*)alloc((size_t)N * 64 * 2);

    unsigned* ebuf = (unsigned*)bufA;            // alias: bufA dead until after CSR build
    unsigned short* hd = (unsigned short*)bufC;  // dinv-scaled h (gather operand)
    unsigned short* xd = hd + (size_t)N * 64;    // dinv-scaled X1 (layers 1,2)
    unsigned short* xA16 = (unsigned short*)bufA;   // layer-1 X1 bf16 (after ebuf dead)
    unsigned short* xB16 = (unsigned short*)bufB;   // layer-1/2/3 X2 bf16
    unsigned short* xd3 = (unsigned short*)bufA;    // layer-3 dinv-scaled X1 (bufA free)
    unsigned short* hD = (unsigned short*)bufD;     // e2 bf16 output (unscaled)

    const int zo_hd = (int)((char*)zpage - (char*)hd);
    const int zo_xd = (int)((char*)zpage - (char*)xd);
    const int zo_xd3 = (int)((char*)zpage - (char*)xd3);
    const int zo_md = (int)((char*)zpage - (char*)md);

    hipMemsetAsync(bcnt, 0, zspan, stream);
    hipMemsetAsync(d_out, 0, (size_t)out_size * 4, stream);

    const int nbw = (N + 3) / 4;
    const int nbt = (N + 63) / 64;
    const int npart = (E + PCHUNK - 1) / PCHUNK;

    // ---- bucketed CSR build (4 launches; k_finish fuses feat->bf16 prescale)
    k_bhist<<<256, 256, 0, stream>>>(dst, bcnt, E);
    k_scanBkt<<<1, 512, 0, stream>>>(bcnt, boff, bcur, nb, E);
    k_partA<<<npart, 256, 0, stream>>>(src, dst, bcur, ebuf, E);
    k_finish<<<nb, 256, 0, stream>>>(ebuf, boff, row_off, dinv, dsq, csr, feat, hd, N, E);

    // ---- Cheb layer 1 (IN=16) + EdgeConv1 stage 1 (fused)
    k_aggr16<<<nbw, 256, 0, stream>>>(hd, nullptr, dinv, row_off, csr, xA16, xd, -1.f, 0.f, zo_hd, N);
    k_aggr16<<<nbw, 256, 0, stream>>>(xd, feat, dinv, row_off, csr, xB16, nullptr, -2.f, -1.f, zo_xd, N);
    k_cheb<16, true, false><<<nbt, 256, 0, stream>>>(feat, xA16, xB16, nullptr, W1, b1,
                                                     Wt1, Wp1, bt1, bp1, md, pbuf, nullptr, nullptr, N);
    k_e2_b<<<nbw, 256, 0, stream>>>(md, pbuf, row_off, csr, dinv, hD, hd, zo_md, N);

    // ---- Cheb layer 2 + EdgeConv2 stage 1 (fused)
    k_aggr64<<<nbw, 256, 0, stream>>>(hd, nullptr, dinv, row_off, csr, nullptr, xd, -1.f, 0.f, zo_hd, N);
    k_aggr64<<<nbw, 256, 0, stream>>>(xd, hD, dinv, row_off, csr, xB16, nullptr, -2.f, -1.f, zo_xd, N);
    k_cheb<64, true, false><<<nbt, 256, 0, stream>>>(hD, xd, xB16, dsq, W2, b2,
                                                     Wt2, Wp2, bt2, bp2, md, pbuf, nullptr, nullptr, N);
    k_e2_b<<<nbw, 256, 0, stream>>>(md, pbuf, row_off, csr, dinv, hD, hd, zo_md, N);

    // ---- Cheb layer 3 with fused atomic mean-pool (xd3 in bufA: no alias with hd)
    k_aggr64<<<nbw, 256, 0, stream>>>(hd, nullptr, dinv, row_off, csr, nullptr, xd3, -1.f, 0.f, zo_hd, N);
    k_aggr64<<<nbw, 256, 0, stream>>>(xd3, hD, dinv, row_off, csr, xB16, nullptr, -2.f, -1.f, zo_xd3, N);
    k_cheb<64, false, true><<<nbt, 256, 0, stream>>>(hD, xd3, xB16, dsq, W3, b3,
                                                     nullptr, nullptr, nullptr, nullptr,
                                                     nullptr, nullptr, gid, out, N);

    // ---- divide by per-graph counts (binary search on sorted gid; no gcnt pass)
    k_div<<<(out_size + 255) / 256, 256, 0, stream>>>(out, gid, N, out_size);
}